// Round 1
// baseline (9180.862 us; speedup 1.0000x reference)
//
#include <hip/hip_runtime.h>
#include <hip/hip_bf16.h>
#include <math.h>

#define BB 32
#define SS 512
#define DD 512
#define HH 8
#define DK 64
#define LL 6
#define NQ 8
#define FF 2048
#define CC 10

// ---------------------------------------------------------------------------
// Kernel 1: h[b,s,d] = emb[x[b,s], d] + pos_encoding(s, d)
// ---------------------------------------------------------------------------
__global__ __launch_bounds__(256) void embed_pe(const int* __restrict__ x,
                                                const float* __restrict__ emb,
                                                float* __restrict__ h) {
    int idx = blockIdx.x * 256 + threadIdx.x;          // 0 .. B*S*D-1
    if (idx >= BB * SS * DD) return;
    int d = idx & (DD - 1);
    int s = (idx >> 9) & (SS - 1);
    int tok = x[idx >> 9];
    int i2 = d >> 1;
    // div = exp( (2i) * (-ln(10000)/D) )
    float freq = expf((float)(2 * i2) * (-9.210340371976184f / (float)DD));
    float ang = (float)s * freq;
    float pe = (d & 1) ? cosf(ang) : sinf(ang);
    h[idx] = emb[(size_t)tok * DD + d] + pe;
}

// ---------------------------------------------------------------------------
// Kernel 2: flash attention, q=k=v=h[b,:,head*64:head*64+64]
// grid: (S/64, H, B), block 256. Each block: 64 query rows, online softmax.
// 4 threads per query row: thread sub in [0,4) owns keys sub*16..+15 (scores)
// and dims sub*16..+15 (PV accumulation).
// ---------------------------------------------------------------------------
__global__ __launch_bounds__(256) void flash_attn(const float* __restrict__ h,
                                                  float* __restrict__ out) {
    __shared__ float Qs[64][65];
    __shared__ float Ks[64][65];
    __shared__ float Ps[64][65];

    int i0 = blockIdx.x * 64;
    int h0 = blockIdx.y * DK;
    int b  = blockIdx.z;
    const float* base = h + (size_t)b * SS * DD;

    int tid = threadIdx.x;
    int r   = tid >> 2;     // query row 0..63
    int sub = tid & 3;      // 0..3

    // load Q tile
    for (int e = tid; e < 64 * 64; e += 256) {
        int rr = e >> 6, d = e & 63;
        Qs[rr][d] = base[(size_t)(i0 + rr) * DD + h0 + d];
    }

    float m = -1e30f, l = 0.f;
    float acc[16];
#pragma unroll
    for (int i = 0; i < 16; i++) acc[i] = 0.f;
    const float scale = 0.125f;  // 1/sqrt(64)

    for (int j0 = 0; j0 < SS; j0 += 64) {
        __syncthreads();   // prev iter done with Ks/Ps; also covers Qs on iter0
        for (int e = tid; e < 64 * 64; e += 256) {
            int rr = e >> 6, d = e & 63;
            Ks[rr][d] = base[(size_t)(j0 + rr) * DD + h0 + d];
        }
        __syncthreads();

        // scores for 16 keys
        float s[16];
#pragma unroll
        for (int jj = 0; jj < 16; jj++) {
            int j = sub * 16 + jj;
            float a = 0.f;
#pragma unroll
            for (int d = 0; d < 64; d++) a = fmaf(Qs[r][d], Ks[j][d], a);
            s[jj] = a * scale;
        }
        // row max across the 4 sub-threads
        float tmax = s[0];
#pragma unroll
        for (int jj = 1; jj < 16; jj++) tmax = fmaxf(tmax, s[jj]);
        tmax = fmaxf(tmax, __shfl_xor(tmax, 1));
        tmax = fmaxf(tmax, __shfl_xor(tmax, 2));
        float newm = fmaxf(m, tmax);
        float alpha = expf(m - newm);
        float tsum = 0.f;
#pragma unroll
        for (int jj = 0; jj < 16; jj++) {
            s[jj] = expf(s[jj] - newm);
            tsum += s[jj];
        }
        tsum += __shfl_xor(tsum, 1);
        tsum += __shfl_xor(tsum, 2);
        l = l * alpha + tsum;
        m = newm;
#pragma unroll
        for (int jj = 0; jj < 16; jj++) Ps[r][sub * 16 + jj] = s[jj];
#pragma unroll
        for (int i = 0; i < 16; i++) acc[i] *= alpha;
        __syncthreads();   // Ps visible

        // PV: acc[dd] += sum_j Ps[r][j] * Ks[j][sub*16+dd]
#pragma unroll
        for (int j = 0; j < 64; j++) {
            float p = Ps[r][j];
#pragma unroll
            for (int dd = 0; dd < 16; dd++)
                acc[dd] = fmaf(p, Ks[j][sub * 16 + dd], acc[dd]);
        }
    }

    float inv = 1.f / l;
#pragma unroll
    for (int dd = 0; dd < 16; dd++)
        out[(size_t)b * SS * DD + (size_t)(i0 + r) * DD + h0 + sub * 16 + dd] = acc[dd] * inv;
}

// ---------------------------------------------------------------------------
// Kernel 3: C = A @ Bm + bias   (fp32, 128x128 tile, KT=16, 8x8 micro-tile)
// ---------------------------------------------------------------------------
__global__ __launch_bounds__(256) void gemm_bias(const float* __restrict__ A,
                                                 const float* __restrict__ Bm,
                                                 const float* __restrict__ bias,
                                                 float* __restrict__ Cm,
                                                 int M, int N, int K) {
    __shared__ float As[16][132];
    __shared__ float Bs[16][132];
    int nb = N / 128;
    int m0 = (blockIdx.x / nb) * 128;
    int n0 = (blockIdx.x % nb) * 128;
    int tid = threadIdx.x;
    int tm = (tid & 15) * 8;
    int tn = (tid >> 4) * 8;
    float acc[8][8] = {};

    for (int k0 = 0; k0 < K; k0 += 16) {
        // A tile (transpose into As[k][m])
#pragma unroll
        for (int i = 0; i < 2; i++) {
            int idx = tid + i * 256;           // 0..511
            int mm = idx >> 2;                 // 0..127
            int kq = (idx & 3) * 4;            // 0,4,8,12
            const float4 v = *reinterpret_cast<const float4*>(&A[(size_t)(m0 + mm) * K + k0 + kq]);
            As[kq + 0][mm] = v.x;
            As[kq + 1][mm] = v.y;
            As[kq + 2][mm] = v.z;
            As[kq + 3][mm] = v.w;
        }
        // B tile
#pragma unroll
        for (int i = 0; i < 2; i++) {
            int idx = tid + i * 256;
            int kk = idx >> 5;                 // 0..15
            int nq = (idx & 31) * 4;           // 0..124
            *reinterpret_cast<float4*>(&Bs[kk][nq]) =
                *reinterpret_cast<const float4*>(&Bm[(size_t)(k0 + kk) * N + n0 + nq]);
        }
        __syncthreads();
#pragma unroll
        for (int kk = 0; kk < 16; kk++) {
            float a[8], bv[8];
#pragma unroll
            for (int i = 0; i < 8; i++) a[i] = As[kk][tm + i];
#pragma unroll
            for (int j = 0; j < 8; j++) bv[j] = Bs[kk][tn + j];
#pragma unroll
            for (int i = 0; i < 8; i++)
#pragma unroll
                for (int j = 0; j < 8; j++)
                    acc[i][j] = fmaf(a[i], bv[j], acc[i][j]);
        }
        __syncthreads();
    }
#pragma unroll
    for (int i = 0; i < 8; i++)
#pragma unroll
        for (int j = 0; j < 8; j++) {
            int n = n0 + tn + j;
            Cm[(size_t)(m0 + tm + i) * N + n] = acc[i][j] + bias[n];
        }
}

// ---------------------------------------------------------------------------
// Kernel 4: h = layernorm(h + add) * g + b   (one wave per 512-elem row)
// ---------------------------------------------------------------------------
__global__ __launch_bounds__(256) void ln_residual(float* __restrict__ h,
                                                   const float* __restrict__ add,
                                                   const float* __restrict__ g,
                                                   const float* __restrict__ bta) {
    int row = blockIdx.x * 4 + (threadIdx.x >> 6);
    int lane = threadIdx.x & 63;
    float* hp = h + (size_t)row * DD;
    const float* ap = add + (size_t)row * DD;
    float v[8];
    float sum = 0.f;
#pragma unroll
    for (int i = 0; i < 8; i++) {
        int d = lane + i * 64;
        v[i] = hp[d] + ap[d];
        sum += v[i];
    }
#pragma unroll
    for (int off = 32; off > 0; off >>= 1) sum += __shfl_xor(sum, off);
    float mu = sum * (1.f / DD);
    float s2 = 0.f;
#pragma unroll
    for (int i = 0; i < 8; i++) {
        float t = v[i] - mu;
        s2 += t * t;
    }
#pragma unroll
    for (int off = 32; off > 0; off >>= 1) s2 += __shfl_xor(s2, off);
    float inv = rsqrtf(s2 * (1.f / DD) + 1e-5f);
#pragma unroll
    for (int i = 0; i < 8; i++) {
        int d = lane + i * 64;
        hp[d] = (v[i] - mu) * inv * g[d] + bta[d];
    }
}

// ---------------------------------------------------------------------------
// Kernel 5: fused FFN:  out = relu(qout @ W1 + b1) @ W2 + b2
//   qout[i,n] = cos(h[i, n]) * cos(theta[n]),  n < 8
// A2 rows generated on the fly inside the K loop of the W2 GEMM.
// ---------------------------------------------------------------------------
__global__ __launch_bounds__(256) void ffn_fused(const float* __restrict__ h,
                                                 const float* __restrict__ W1,
                                                 const float* __restrict__ b1,
                                                 const float* __restrict__ W2,
                                                 const float* __restrict__ b2,
                                                 const float* __restrict__ theta,
                                                 float* __restrict__ out) {
    __shared__ float As[16][132];
    __shared__ float Bs[16][132];
    __shared__ float qs[128][9];
    __shared__ float tcos[8];

    int nb = DD / 128;                       // 4
    int m0 = (blockIdx.x / nb) * 128;
    int n0 = (blockIdx.x % nb) * 128;
    int tid = threadIdx.x;

    if (tid < 8) tcos[tid] = cosf(theta[tid]);
    __syncthreads();
    // qout rows for this block
#pragma unroll
    for (int i = 0; i < 4; i++) {
        int idx = tid + i * 256;             // 0..1023
        int mm = idx >> 3, n = idx & 7;
        qs[mm][n] = cosf(h[(size_t)(m0 + mm) * DD + n]) * tcos[n];
    }
    __syncthreads();

    int tm = (tid & 15) * 8;
    int tn = (tid >> 4) * 8;
    int kkA = tid & 15;                      // this thread's k within the tile
    int mbA = tid >> 4;                      // 0..15
    float acc[8][8] = {};

    for (int k0 = 0; k0 < FF; k0 += 16) {
        // this thread's W1 column (8 values) + b1 for k = k0+kkA
        float w1v[8];
#pragma unroll
        for (int n = 0; n < 8; n++) w1v[n] = W1[n * FF + k0 + kkA];
        float b1v = b1[k0 + kkA];
        // B tile from W2
#pragma unroll
        for (int i = 0; i < 2; i++) {
            int idx = tid + i * 256;
            int kk = idx >> 5;
            int nq = (idx & 31) * 4;
            *reinterpret_cast<float4*>(&Bs[kk][nq]) =
                *reinterpret_cast<const float4*>(&W2[(size_t)(k0 + kk) * DD + n0 + nq]);
        }
        // A2 tile: relu(qs @ w1 + b1)
#pragma unroll
        for (int i = 0; i < 8; i++) {
            int mm = mbA + i * 16;
            float v = b1v;
#pragma unroll
            for (int n = 0; n < 8; n++) v = fmaf(qs[mm][n], w1v[n], v);
            As[kkA][mm] = fmaxf(v, 0.f);
        }
        __syncthreads();
#pragma unroll
        for (int kk = 0; kk < 16; kk++) {
            float a[8], bv[8];
#pragma unroll
            for (int i = 0; i < 8; i++) a[i] = As[kk][tm + i];
#pragma unroll
            for (int j = 0; j < 8; j++) bv[j] = Bs[kk][tn + j];
#pragma unroll
            for (int i = 0; i < 8; i++)
#pragma unroll
                for (int j = 0; j < 8; j++)
                    acc[i][j] = fmaf(a[i], bv[j], acc[i][j]);
        }
        __syncthreads();
    }
#pragma unroll
    for (int i = 0; i < 8; i++)
#pragma unroll
        for (int j = 0; j < 8; j++) {
            int n = n0 + tn + j;
            out[(size_t)(m0 + tm + i) * DD + n] = acc[i][j] + b2[n];
        }
}

// ---------------------------------------------------------------------------
// Kernel 6: pooled[b,d] = mean_s h[b,s,d]
// ---------------------------------------------------------------------------
__global__ __launch_bounds__(256) void pool_mean(const float* __restrict__ h,
                                                 float* __restrict__ pooled) {
    int idx = blockIdx.x * 256 + threadIdx.x;   // b*512 + d
    if (idx >= BB * DD) return;
    int b = idx >> 9, d = idx & 511;
    float s = 0.f;
    for (int j = 0; j < SS; j++) s += h[((size_t)b * SS + j) * DD + d];
    pooled[idx] = s * (1.f / SS);
}

// ---------------------------------------------------------------------------
// Kernel 7: out[b,c] = pooled[b,:] . clf_w[:,c] + clf_b[c]
// ---------------------------------------------------------------------------
__global__ __launch_bounds__(64) void classifier(const float* __restrict__ pooled,
                                                 const float* __restrict__ W,
                                                 const float* __restrict__ bias,
                                                 float* __restrict__ out) {
    int o = blockIdx.x;                 // 0..319
    int b = o / CC, c = o % CC;
    int lane = threadIdx.x;
    float s = 0.f;
    for (int d = lane; d < DD; d += 64) s += pooled[b * DD + d] * W[d * CC + c];
#pragma unroll
    for (int off = 32; off > 0; off >>= 1) s += __shfl_xor(s, off);
    if (lane == 0) out[o] = s + bias[c];
}

// ---------------------------------------------------------------------------
extern "C" void kernel_launch(void* const* d_in, const int* in_sizes, int n_in,
                              void* d_out, int out_size, void* d_ws, size_t ws_size,
                              hipStream_t stream) {
    (void)in_sizes; (void)n_in; (void)out_size; (void)ws_size;
    const int*   x      = (const int*)d_in[0];
    const float* emb    = (const float*)d_in[1];
    const float* ln1_g  = (const float*)d_in[2];
    const float* ln1_b  = (const float*)d_in[3];
    const float* ln2_g  = (const float*)d_in[4];
    const float* ln2_b  = (const float*)d_in[5];
    const float* attn_w = (const float*)d_in[6];
    const float* attn_b = (const float*)d_in[7];
    const float* theta  = (const float*)d_in[8];
    const float* ffn_w1 = (const float*)d_in[9];
    const float* ffn_b1 = (const float*)d_in[10];
    const float* ffn_w2 = (const float*)d_in[11];
    const float* ffn_b2 = (const float*)d_in[12];
    const float* clf_w  = (const float*)d_in[13];
    const float* clf_b  = (const float*)d_in[14];
    float* out = (float*)d_out;

    char* ws = (char*)d_ws;
    float* h      = (float*)(ws);                 // 32 MB
    float* t1     = (float*)(ws + 33554432);      // 32 MB
    float* t2     = (float*)(ws + 67108864);      // 32 MB
    float* pooled = (float*)(ws + 100663296);     // 64 KB

    embed_pe<<<(BB * SS * DD + 255) / 256, 256, 0, stream>>>(x, emb, h);

    for (int l = 0; l < LL; l++) {
        flash_attn<<<dim3(SS / 64, HH, BB), 256, 0, stream>>>(h, t1);
        gemm_bias<<<(16384 / 128) * (DD / 128), 256, 0, stream>>>(
            t1, attn_w + (size_t)l * DD * DD, attn_b + l * DD, t2, BB * SS, DD, DD);
        ln_residual<<<BB * SS / 4, 256, 0, stream>>>(h, t2, ln1_g + l * DD, ln1_b + l * DD);
        ffn_fused<<<(16384 / 128) * (DD / 128), 256, 0, stream>>>(
            h, ffn_w1 + (size_t)l * NQ * FF, ffn_b1 + l * FF,
            ffn_w2 + (size_t)l * FF * DD, ffn_b2 + l * DD, theta + l * NQ, t1);
        ln_residual<<<BB * SS / 4, 256, 0, stream>>>(h, t1, ln2_g + l * DD, ln2_b + l * DD);
    }

    pool_mean<<<(BB * DD + 255) / 256, 256, 0, stream>>>(h, pooled);
    classifier<<<BB * CC, 64, 0, stream>>>(pooled, clf_w, clf_b, out);
}

// Round 3
// 2704.804 us; speedup vs baseline: 3.3943x; 3.3943x over previous
//
#include <hip/hip_runtime.h>
#include <hip/hip_bf16.h>
#include <math.h>

#define BB 32
#define SS 512
#define DD 512
#define HH 8
#define DK 64
#define LL 6
#define NQ 8
#define FF 2048
#define CC 10

typedef unsigned int uint;
typedef unsigned short ushort_t;
using bf16x8 = __attribute__((ext_vector_type(8))) short;
using f32x4  = __attribute__((ext_vector_type(4))) float;

#define MFMA(a, b, c) __builtin_amdgcn_mfma_f32_16x16x32_bf16((a), (b), (c), 0, 0, 0)

__device__ inline ushort_t f2bf(float x) {           // fp32 -> bf16, RNE
    uint u = __float_as_uint(x);
    u += 0x7FFFu + ((u >> 16) & 1u);
    return (ushort_t)(u >> 16);
}
__device__ inline float bf2f(ushort_t b) { return __uint_as_float(((uint)b) << 16); }
__device__ inline void split2(float v, ushort_t& hi, ushort_t& lo) {
    hi = f2bf(v);
    lo = f2bf(v - bf2f(hi));
}

// ---------------------------------------------------------------------------
// Kernel 1: h[b,s,d] = emb[x[b,s], d] + pos_encoding(s, d)   (fp32)
// ---------------------------------------------------------------------------
__global__ __launch_bounds__(256) void embed_pe(const int* __restrict__ x,
                                                const float* __restrict__ emb,
                                                float* __restrict__ h) {
    int idx = blockIdx.x * 256 + threadIdx.x;
    if (idx >= BB * SS * DD) return;
    int d = idx & (DD - 1);
    int s = (idx >> 9) & (SS - 1);
    int tok = x[idx >> 9];
    int i2 = d >> 1;
    float freq = expf((float)(2 * i2) * (-9.210340371976184f / (float)DD));
    float ang = (float)s * freq;
    float pe = (d & 1) ? cosf(ang) : sinf(ang);
    h[idx] = emb[(size_t)tok * DD + d] + pe;
}

// ---------------------------------------------------------------------------
// Kernel 2: split-precision MFMA flash attention. q=k=v=h[b,:,head*64..+63].
// grid (S/64, H, B), 4 waves, wave w owns q-rows w*16..+15.
// Every matmul is a 3-term bf16 hi/lo product (error ~2e-5 rel).
// Output written as TWO bf16 planes (hi, lo) for the proj GEMM.
// ---------------------------------------------------------------------------
__global__ __launch_bounds__(256, 2) void flash_attn_split(const float* __restrict__ h,
                                                           ushort_t* __restrict__ outh,
                                                           ushort_t* __restrict__ outl) {
    __shared__ __align__(16) ushort_t Qh[64][72], Ql[64][72];
    __shared__ __align__(16) ushort_t Kh[64][72], Kl[64][72];
    __shared__ __align__(16) ushort_t Vh[64][72], Vl[64][72];   // [dd][j]
    __shared__ __align__(16) ushort_t Ph[64][72], Pl[64][72];

    int i0 = blockIdx.x * 64;
    int h0 = blockIdx.y * DK;
    int b  = blockIdx.z;
    const float* base = h + (size_t)b * (SS * DD);

    int t = threadIdx.x;
    int w = t >> 6;
    int ln = t & 63;
    int l15 = ln & 15, lh = ln >> 4;

    // stage Q (scaled by 1/8), hi/lo split
    {
        int r = t >> 2, cb = (t & 3) << 4;
        const float* src = &base[(size_t)(i0 + r) * DD + h0 + cb];
#pragma unroll
        for (int c = 0; c < 4; c++) {
            float4 v = *reinterpret_cast<const float4*>(src + 4 * c);
            float vv[4] = {v.x * 0.125f, v.y * 0.125f, v.z * 0.125f, v.w * 0.125f};
#pragma unroll
            for (int e = 0; e < 4; e++) {
                ushort_t hb, lb; split2(vv[e], hb, lb);
                Qh[r][cb + 4 * c + e] = hb;
                Ql[r][cb + 4 * c + e] = lb;
            }
        }
    }

    float m_[4], l_[4], al[4];
    f32x4 acc[4];
    f32x4 z4 = {0.f, 0.f, 0.f, 0.f};
#pragma unroll
    for (int r = 0; r < 4; r++) { m_[r] = -1e30f; l_[r] = 0.f; acc[r] = z4; }

    for (int j0 = 0; j0 < SS; j0 += 64) {
        __syncthreads();
        // stage K (hi/lo) + V (transposed, hi/lo)
        {
            int r = t >> 2, cb = (t & 3) << 4;
            const float* src = &base[(size_t)(j0 + r) * DD + h0 + cb];
#pragma unroll
            for (int c = 0; c < 4; c++) {
                float4 v = *reinterpret_cast<const float4*>(src + 4 * c);
                float vv[4] = {v.x, v.y, v.z, v.w};
#pragma unroll
                for (int e = 0; e < 4; e++) {
                    ushort_t hb, lb; split2(vv[e], hb, lb);
                    int d = cb + 4 * c + e;
                    Kh[r][d] = hb; Kl[r][d] = lb;
                    Vh[d][r] = hb; Vl[d][r] = lb;
                }
            }
        }
        __syncthreads();

        // scores: 3-term split product, S = Qh(Kh+Kl) + Ql*Kh
        f32x4 sc[4];
        bf16x8 aqh0 = *reinterpret_cast<const bf16x8*>(&Qh[w * 16 + l15][lh * 8]);
        bf16x8 aqh1 = *reinterpret_cast<const bf16x8*>(&Qh[w * 16 + l15][32 + lh * 8]);
        bf16x8 aql0 = *reinterpret_cast<const bf16x8*>(&Ql[w * 16 + l15][lh * 8]);
        bf16x8 aql1 = *reinterpret_cast<const bf16x8*>(&Ql[w * 16 + l15][32 + lh * 8]);
#pragma unroll
        for (int tt = 0; tt < 4; tt++) {
            bf16x8 bh0 = *reinterpret_cast<const bf16x8*>(&Kh[tt * 16 + l15][lh * 8]);
            bf16x8 bh1 = *reinterpret_cast<const bf16x8*>(&Kh[tt * 16 + l15][32 + lh * 8]);
            bf16x8 bl0 = *reinterpret_cast<const bf16x8*>(&Kl[tt * 16 + l15][lh * 8]);
            bf16x8 bl1 = *reinterpret_cast<const bf16x8*>(&Kl[tt * 16 + l15][32 + lh * 8]);
            f32x4 s = z4;
            s = MFMA(aqh0, bh0, s);
            s = MFMA(aqh1, bh1, s);
            s = MFMA(aqh0, bl0, s);
            s = MFMA(aqh1, bl1, s);
            s = MFMA(aql0, bh0, s);
            s = MFMA(aql1, bh1, s);
            sc[tt] = s;
        }

        // online softmax per row (row = w*16 + lh*4 + r; cols over tt, l15)
#pragma unroll
        for (int r = 0; r < 4; r++) {
            float mx = fmaxf(fmaxf(sc[0][r], sc[1][r]), fmaxf(sc[2][r], sc[3][r]));
            mx = fmaxf(mx, __shfl_xor(mx, 1));
            mx = fmaxf(mx, __shfl_xor(mx, 2));
            mx = fmaxf(mx, __shfl_xor(mx, 4));
            mx = fmaxf(mx, __shfl_xor(mx, 8));
            float nm = fmaxf(m_[r], mx);
            al[r] = __expf(m_[r] - nm);
            m_[r] = nm;
            float rs = 0.f;
#pragma unroll
            for (int tt = 0; tt < 4; tt++) {
                float p = __expf(sc[tt][r] - nm);
                sc[tt][r] = p;
                rs += p;
            }
            rs += __shfl_xor(rs, 1);
            rs += __shfl_xor(rs, 2);
            rs += __shfl_xor(rs, 4);
            rs += __shfl_xor(rs, 8);
            l_[r] = l_[r] * al[r] + rs;
        }
        // write P hi/lo (own wave's rows only -> within-wave dep, compiler waits)
#pragma unroll
        for (int tt = 0; tt < 4; tt++)
#pragma unroll
            for (int r = 0; r < 4; r++) {
                ushort_t hb, lb; split2(sc[tt][r], hb, lb);
                Ph[w * 16 + lh * 4 + r][tt * 16 + l15] = hb;
                Pl[w * 16 + lh * 4 + r][tt * 16 + l15] = lb;
            }
        // rescale accumulator
#pragma unroll
        for (int td = 0; td < 4; td++) {
            acc[td][0] *= al[0];
            acc[td][1] *= al[1];
            acc[td][2] *= al[2];
            acc[td][3] *= al[3];
        }
        // PV: 3-term split
        bf16x8 aph0 = *reinterpret_cast<const bf16x8*>(&Ph[w * 16 + l15][lh * 8]);
        bf16x8 aph1 = *reinterpret_cast<const bf16x8*>(&Ph[w * 16 + l15][32 + lh * 8]);
        bf16x8 apl0 = *reinterpret_cast<const bf16x8*>(&Pl[w * 16 + l15][lh * 8]);
        bf16x8 apl1 = *reinterpret_cast<const bf16x8*>(&Pl[w * 16 + l15][32 + lh * 8]);
#pragma unroll
        for (int td = 0; td < 4; td++) {
            bf16x8 bvh0 = *reinterpret_cast<const bf16x8*>(&Vh[td * 16 + l15][lh * 8]);
            bf16x8 bvh1 = *reinterpret_cast<const bf16x8*>(&Vh[td * 16 + l15][32 + lh * 8]);
            bf16x8 bvl0 = *reinterpret_cast<const bf16x8*>(&Vl[td * 16 + l15][lh * 8]);
            bf16x8 bvl1 = *reinterpret_cast<const bf16x8*>(&Vl[td * 16 + l15][32 + lh * 8]);
            acc[td] = MFMA(aph0, bvh0, acc[td]);
            acc[td] = MFMA(aph1, bvh1, acc[td]);
            acc[td] = MFMA(aph0, bvl0, acc[td]);
            acc[td] = MFMA(aph1, bvl1, acc[td]);
            acc[td] = MFMA(apl0, bvh0, acc[td]);
            acc[td] = MFMA(apl1, bvh1, acc[td]);
        }
    }

#pragma unroll
    for (int r = 0; r < 4; r++) {
        float inv = 1.f / l_[r];
        int row = i0 + w * 16 + lh * 4 + r;
#pragma unroll
        for (int td = 0; td < 4; td++) {
            float o = acc[td][r] * inv;
            ushort_t hb, lb; split2(o, hb, lb);
            size_t idx = (size_t)b * SS * DD + (size_t)row * DD + h0 + td * 16 + l15;
            outh[idx] = hb;
            outl[idx] = lb;
        }
    }
}

// ---------------------------------------------------------------------------
// Kernel 3: C[M][N] fp32 = A(hi/lo bf16 planes, [M][K]) @ B(fp32 [K][N]) + bias
// B is transposed + hi/lo split into LDS in-kernel. 3-term MFMA product.
// 128x128 tile, BK=64, 4 waves (2x2), 64x64 per wave.
// ---------------------------------------------------------------------------
__global__ __launch_bounds__(256, 2) void gemm_split(const ushort_t* __restrict__ Ah,
                                                     const ushort_t* __restrict__ Al,
                                                     const float* __restrict__ Bsrc,
                                                     const float* __restrict__ bias,
                                                     float* __restrict__ C,
                                                     int M, int N, int K) {
    __shared__ __align__(16) ushort_t Abh[128][72], Abl[128][72];
    __shared__ __align__(16) ushort_t Bbh[128][72], Bbl[128][72];
    int nb = N >> 7;
    int m0 = ((int)blockIdx.x / nb) << 7;
    int n0 = ((int)blockIdx.x % nb) << 7;
    int t = threadIdx.x;
    int w = t >> 6, ln = t & 63, l15 = ln & 15, lh = ln >> 4;
    int wr = (w >> 1) * 64, wc = (w & 1) * 64;

    f32x4 z4 = {0.f, 0.f, 0.f, 0.f};
    f32x4 acc[4][4];
#pragma unroll
    for (int i = 0; i < 4; i++)
#pragma unroll
        for (int j = 0; j < 4; j++) acc[i][j] = z4;

    int arr = t >> 3, akk = (t & 7) * 8;   // A staging: 4 rows x 8 bf16
    int bn = t >> 1, bkh = (t & 1) * 32;   // B staging: 1 col, 32 k

    for (int k0 = 0; k0 < K; k0 += 64) {
        __syncthreads();
#pragma unroll
        for (int r = 0; r < 4; r++) {
            int row = arr + r * 32;
            *reinterpret_cast<uint4*>(&Abh[row][akk]) =
                *reinterpret_cast<const uint4*>(&Ah[(size_t)(m0 + row) * K + k0 + akk]);
            *reinterpret_cast<uint4*>(&Abl[row][akk]) =
                *reinterpret_cast<const uint4*>(&Al[(size_t)(m0 + row) * K + k0 + akk]);
        }
#pragma unroll
        for (int c = 0; c < 4; c++) {
            union { ushort_t u[8]; bf16x8 v; } ph, pl;
#pragma unroll
            for (int e = 0; e < 8; e++) {
                float f = Bsrc[(size_t)(k0 + bkh + 8 * c + e) * N + n0 + bn];
                ushort_t hb, lb; split2(f, hb, lb);
                ph.u[e] = hb; pl.u[e] = lb;
            }
            *reinterpret_cast<bf16x8*>(&Bbh[bn][bkh + 8 * c]) = ph.v;
            *reinterpret_cast<bf16x8*>(&Bbl[bn][bkh + 8 * c]) = pl.v;
        }
        __syncthreads();
#pragma unroll
        for (int ks = 0; ks < 2; ks++) {
            bf16x8 ah[4], al_[4];
#pragma unroll
            for (int mt = 0; mt < 4; mt++) {
                ah[mt]  = *reinterpret_cast<const bf16x8*>(&Abh[wr + mt * 16 + l15][ks * 32 + lh * 8]);
                al_[mt] = *reinterpret_cast<const bf16x8*>(&Abl[wr + mt * 16 + l15][ks * 32 + lh * 8]);
            }
#pragma unroll
            for (int nt = 0; nt < 4; nt++) {
                bf16x8 bh = *reinterpret_cast<const bf16x8*>(&Bbh[wc + nt * 16 + l15][ks * 32 + lh * 8]);
                bf16x8 bl = *reinterpret_cast<const bf16x8*>(&Bbl[wc + nt * 16 + l15][ks * 32 + lh * 8]);
#pragma unroll
                for (int mt = 0; mt < 4; mt++) {
                    acc[mt][nt] = MFMA(ah[mt], bh, acc[mt][nt]);
                    acc[mt][nt] = MFMA(ah[mt], bl, acc[mt][nt]);
                    acc[mt][nt] = MFMA(al_[mt], bh, acc[mt][nt]);
                }
            }
        }
    }
#pragma unroll
    for (int nt = 0; nt < 4; nt++) {
        int col = n0 + wc + nt * 16 + l15;
        float bs = bias[col];
#pragma unroll
        for (int mt = 0; mt < 4; mt++)
#pragma unroll
            for (int r = 0; r < 4; r++)
                C[(size_t)(m0 + wr + mt * 16 + lh * 4 + r) * N + col] = acc[mt][nt][r] + bs;
    }
}

// ---------------------------------------------------------------------------
// Kernel 4: h = layernorm(h + add) * g + b   (one wave per 512-elem row, fp32)
// ---------------------------------------------------------------------------
__global__ __launch_bounds__(256) void ln_residual(float* __restrict__ h,
                                                   const float* __restrict__ add,
                                                   const float* __restrict__ g,
                                                   const float* __restrict__ bta) {
    int row = blockIdx.x * 4 + (threadIdx.x >> 6);
    int lane = threadIdx.x & 63;
    float* hp = h + (size_t)row * DD;
    const float* ap = add + (size_t)row * DD;
    float v[8];
    float sum = 0.f;
#pragma unroll
    for (int i = 0; i < 8; i++) {
        int d = lane + i * 64;
        v[i] = hp[d] + ap[d];
        sum += v[i];
    }
#pragma unroll
    for (int off = 32; off > 0; off >>= 1) sum += __shfl_xor(sum, off);
    float mu = sum * (1.f / DD);
    float s2 = 0.f;
#pragma unroll
    for (int i = 0; i < 8; i++) {
        float d2 = v[i] - mu;
        s2 += d2 * d2;
    }
#pragma unroll
    for (int off = 32; off > 0; off >>= 1) s2 += __shfl_xor(s2, off);
    float inv = rsqrtf(s2 * (1.f / DD) + 1e-5f);
#pragma unroll
    for (int i = 0; i < 8; i++) {
        int d = lane + i * 64;
        hp[d] = (v[i] - mu) * inv * g[d] + bta[d];
    }
}

// ---------------------------------------------------------------------------
// Kernel 5: fused FFN: out = relu(qout @ W1 + b1) @ W2 + b2, qout=cos(h)*cos(th)
// A1 computed fp32 (K=8 dot), split hi/lo; W2 transposed+split in LDS.
// 128x128 tile, BK=64, 3-term MFMA.
// ---------------------------------------------------------------------------
__global__ __launch_bounds__(256, 2) void ffn_split(const float* __restrict__ h,
                                                    const float* __restrict__ W1,
                                                    const float* __restrict__ b1,
                                                    const float* __restrict__ W2,
                                                    const float* __restrict__ b2,
                                                    const float* __restrict__ theta,
                                                    float* __restrict__ outp) {
    __shared__ __align__(16) ushort_t Abh[128][72], Abl[128][72];
    __shared__ __align__(16) ushort_t Bbh[128][72], Bbl[128][72];
    __shared__ __align__(16) float qs[128][12];
    __shared__ float tcs[8];

    int t = threadIdx.x;
    int m0 = (int)(blockIdx.x >> 2) * 128;
    int n0 = (int)(blockIdx.x & 3) * 128;
    if (t < 8) tcs[t] = cosf(theta[t]);
    __syncthreads();
#pragma unroll
    for (int i = 0; i < 4; i++) {
        int idx = t + i * 256;
        int m = idx >> 3, n = idx & 7;
        qs[m][n] = cosf(h[(size_t)(m0 + m) * DD + n]) * tcs[n];
    }

    int w = t >> 6, ln = t & 63, l15 = ln & 15, lh = ln >> 4;
    int wr = (w >> 1) * 64, wc = (w & 1) * 64;
    f32x4 z4 = {0.f, 0.f, 0.f, 0.f};
    f32x4 acc[4][4];
#pragma unroll
    for (int i = 0; i < 4; i++)
#pragma unroll
        for (int j = 0; j < 4; j++) acc[i][j] = z4;

    int akk = t & 63, amg = (t >> 6) * 32;   // A2 gen
    int bn = t >> 1, bkh = (t & 1) * 32;     // B staging

    for (int k0 = 0; k0 < FF; k0 += 64) {
        __syncthreads();
        // A2 panel: relu(qs @ W1 + b1) -> hi/lo split
        float w1v[8];
#pragma unroll
        for (int n = 0; n < 8; n++) w1v[n] = W1[n * FF + k0 + akk];
        float b1v = b1[k0 + akk];
#pragma unroll 4
        for (int i = 0; i < 32; i++) {
            int m = amg + i;
            float4 q0 = *reinterpret_cast<const float4*>(&qs[m][0]);
            float4 q1 = *reinterpret_cast<const float4*>(&qs[m][4]);
            float v = b1v;
            v = fmaf(q0.x, w1v[0], v);
            v = fmaf(q0.y, w1v[1], v);
            v = fmaf(q0.z, w1v[2], v);
            v = fmaf(q0.w, w1v[3], v);
            v = fmaf(q1.x, w1v[4], v);
            v = fmaf(q1.y, w1v[5], v);
            v = fmaf(q1.z, w1v[6], v);
            v = fmaf(q1.w, w1v[7], v);
            v = fmaxf(v, 0.f);
            ushort_t hb, lb; split2(v, hb, lb);
            Abh[m][akk] = hb;
            Abl[m][akk] = lb;
        }
        // B panel from W2 fp32 [FF][DD]: transpose + split
#pragma unroll
        for (int c = 0; c < 4; c++) {
            union { ushort_t u[8]; bf16x8 v; } ph, pl;
#pragma unroll
            for (int e = 0; e < 8; e++) {
                float f = W2[(size_t)(k0 + bkh + 8 * c + e) * DD + n0 + bn];
                ushort_t hb, lb; split2(f, hb, lb);
                ph.u[e] = hb; pl.u[e] = lb;
            }
            *reinterpret_cast<bf16x8*>(&Bbh[bn][bkh + 8 * c]) = ph.v;
            *reinterpret_cast<bf16x8*>(&Bbl[bn][bkh + 8 * c]) = pl.v;
        }
        __syncthreads();
#pragma unroll
        for (int ks = 0; ks < 2; ks++) {
            bf16x8 ah[4], al_[4];
#pragma unroll
            for (int mt = 0; mt < 4; mt++) {
                ah[mt]  = *reinterpret_cast<const bf16x8*>(&Abh[wr + mt * 16 + l15][ks * 32 + lh * 8]);
                al_[mt] = *reinterpret_cast<const bf16x8*>(&Abl[wr + mt * 16 + l15][ks * 32 + lh * 8]);
            }
#pragma unroll
            for (int nt = 0; nt < 4; nt++) {
                bf16x8 bh = *reinterpret_cast<const bf16x8*>(&Bbh[wc + nt * 16 + l15][ks * 32 + lh * 8]);
                bf16x8 bl = *reinterpret_cast<const bf16x8*>(&Bbl[wc + nt * 16 + l15][ks * 32 + lh * 8]);
#pragma unroll
                for (int mt = 0; mt < 4; mt++) {
                    acc[mt][nt] = MFMA(ah[mt], bh, acc[mt][nt]);
                    acc[mt][nt] = MFMA(ah[mt], bl, acc[mt][nt]);
                    acc[mt][nt] = MFMA(al_[mt], bh, acc[mt][nt]);
                }
            }
        }
    }
#pragma unroll
    for (int nt = 0; nt < 4; nt++) {
        int col = n0 + wc + nt * 16 + l15;
        float bs = b2[col];
#pragma unroll
        for (int mt = 0; mt < 4; mt++)
#pragma unroll
            for (int r = 0; r < 4; r++)
                outp[(size_t)(m0 + wr + mt * 16 + lh * 4 + r) * DD + col] = acc[mt][nt][r] + bs;
    }
}

// ---------------------------------------------------------------------------
// Kernel 6: pooled[b,d] = mean_s h[b,s,d]
// ---------------------------------------------------------------------------
__global__ __launch_bounds__(256) void pool_mean(const float* __restrict__ h,
                                                 float* __restrict__ pooled) {
    int idx = blockIdx.x * 256 + threadIdx.x;
    if (idx >= BB * DD) return;
    int b = idx >> 9, d = idx & 511;
    float s = 0.f;
    for (int j = 0; j < SS; j++) s += h[((size_t)b * SS + j) * DD + d];
    pooled[idx] = s * (1.f / SS);
}

// ---------------------------------------------------------------------------
// Kernel 7: out[b,c] = pooled[b,:] . clf_w[:,c] + clf_b[c]
// ---------------------------------------------------------------------------
__global__ __launch_bounds__(64) void classifier(const float* __restrict__ pooled,
                                                 const float* __restrict__ W,
                                                 const float* __restrict__ bias,
                                                 float* __restrict__ out) {
    int o = blockIdx.x;
    int b = o / CC, c = o % CC;
    int lane = threadIdx.x;
    float s = 0.f;
    for (int d = lane; d < DD; d += 64) s += pooled[b * DD + d] * W[d * CC + c];
#pragma unroll
    for (int off = 32; off > 0; off >>= 1) s += __shfl_xor(s, off);
    if (lane == 0) out[o] = s + bias[c];
}

// ---------------------------------------------------------------------------
extern "C" void kernel_launch(void* const* d_in, const int* in_sizes, int n_in,
                              void* d_out, int out_size, void* d_ws, size_t ws_size,
                              hipStream_t stream) {
    (void)in_sizes; (void)n_in; (void)out_size; (void)ws_size;
    const int*   x      = (const int*)d_in[0];
    const float* emb    = (const float*)d_in[1];
    const float* ln1_g  = (const float*)d_in[2];
    const float* ln1_b  = (const float*)d_in[3];
    const float* ln2_g  = (const float*)d_in[4];
    const float* ln2_b  = (const float*)d_in[5];
    const float* attn_w = (const float*)d_in[6];
    const float* attn_b = (const float*)d_in[7];
    const float* theta  = (const float*)d_in[8];
    const float* ffn_w1 = (const float*)d_in[9];
    const float* ffn_b1 = (const float*)d_in[10];
    const float* ffn_w2 = (const float*)d_in[11];
    const float* ffn_b2 = (const float*)d_in[12];
    const float* clf_w  = (const float*)d_in[13];
    const float* clf_b  = (const float*)d_in[14];
    float* out = (float*)d_out;

    char* ws = (char*)d_ws;
    float*    h      = (float*)(ws);                    // 32 MB fp32
    float*    t2     = (float*)(ws + 33554432);         // 32 MB fp32
    ushort_t* t1h    = (ushort_t*)(ws + 67108864);      // 16 MB bf16 hi
    ushort_t* t1l    = (ushort_t*)(ws + 83886080);      // 16 MB bf16 lo
    float*    pooled = (float*)(ws + 100663296);        // 64 KB

    embed_pe<<<(BB * SS * DD + 255) / 256, 256, 0, stream>>>(x, emb, h);

    for (int l = 0; l < LL; l++) {
        flash_attn_split<<<dim3(SS / 64, HH, BB), 256, 0, stream>>>(h, t1h, t1l);
        gemm_split<<<(16384 / 128) * (DD / 128), 256, 0, stream>>>(
            t1h, t1l, attn_w + (size_t)l * DD * DD, attn_b + l * DD, t2, BB * SS, DD, DD);
        ln_residual<<<BB * SS / 4, 256, 0, stream>>>(h, t2, ln1_g + l * DD, ln1_b + l * DD);
        ffn_split<<<(16384 / 128) * 4, 256, 0, stream>>>(
            h, ffn_w1 + (size_t)l * NQ * FF, ffn_b1 + l * FF,
            ffn_w2 + (size_t)l * FF * DD, ffn_b2 + l * DD, theta + l * NQ, t2);
        ln_residual<<<BB * SS / 4, 256, 0, stream>>>(h, t2, ln2_g + l * DD, ln2_b + l * DD);
    }

    pool_mean<<<(BB * DD + 255) / 256, 256, 0, stream>>>(h, pooled);
    classifier<<<BB * CC, 64, 0, stream>>>(pooled, clf_w, clf_b, out);
}

// Round 5
// 2677.188 us; speedup vs baseline: 3.4293x; 1.0103x over previous
//
#include <hip/hip_runtime.h>
#include <hip/hip_bf16.h>
#include <math.h>

#define BB 32
#define SS 512
#define DD 512
#define HH 8
#define DK 64
#define LL 6
#define NQ 8
#define FF 2048
#define CC 10

typedef unsigned int uint;
typedef unsigned short ushort_t;
using bf16x8 = __attribute__((ext_vector_type(8))) short;
using f32x4  = __attribute__((ext_vector_type(4))) float;

#define MFMA(a, b, c) __builtin_amdgcn_mfma_f32_16x16x32_bf16((a), (b), (c), 0, 0, 0)

union U8 { ushort_t u[8]; bf16x8 v; };

__device__ inline ushort_t f2bf(float x) {           // fp32 -> bf16, RNE
    uint u = __float_as_uint(x);
    u += 0x7FFFu + ((u >> 16) & 1u);
    return (ushort_t)(u >> 16);
}
// truncation split: hi = top 16 bits, lo = RNE(residual); hi+lo = v to ~2^-17 rel
__device__ inline void tsplit(float v, ushort_t& hi, ushort_t& lo) {
    uint u = __float_as_uint(v);
    hi = (ushort_t)(u >> 16);
    lo = f2bf(v - __uint_as_float(u & 0xFFFF0000u));
}
__device__ inline uint packsplit(float v) {
    uint u = __float_as_uint(v) & 0xFFFF0000u;
    uint ru = __float_as_uint(v - __uint_as_float(u));
    ru += 0x7FFFu + ((ru >> 16) & 1u);
    return u | (ru >> 16);
}
__device__ inline float unpackf(uint u) {
    return __uint_as_float(u & 0xFFFF0000u) + __uint_as_float(u << 16);
}

// ---------------------------------------------------------------------------
// Kernel 1: h[b,s,d] = emb[x[b,s], d] + pe(s,d), stored packed hi|lo bf16
// ---------------------------------------------------------------------------
__global__ __launch_bounds__(256) void embed_pe(const int* __restrict__ x,
                                                const float* __restrict__ emb,
                                                uint* __restrict__ Hp) {
    int idx = blockIdx.x * 256 + threadIdx.x;
    if (idx >= BB * SS * DD) return;
    int d = idx & (DD - 1);
    int s = (idx >> 9) & (SS - 1);
    int tok = x[idx >> 9];
    int i2 = d >> 1;
    float freq = expf((float)(2 * i2) * (-9.210340371976184f / (float)DD));
    float ang = (float)s * freq;
    float pe = (d & 1) ? cosf(ang) : sinf(ang);
    Hp[idx] = packsplit(emb[(size_t)tok * DD + d] + pe);
}

// ---------------------------------------------------------------------------
// Kernel 2: split-precision MFMA flash attention on packed h.
// grid (S/64, H, B), 4 waves; every matmul = 3-term bf16 hi/lo product.
// Scores scaled by 1/8 AFTER MFMA (linear). Output -> two bf16 planes.
// ---------------------------------------------------------------------------
__global__ __launch_bounds__(256, 2) void flash_attn_split(const uint* __restrict__ Hp,
                                                           ushort_t* __restrict__ outh,
                                                           ushort_t* __restrict__ outl) {
    __shared__ __align__(16) ushort_t Qh[64][72], Ql[64][72];
    __shared__ __align__(16) ushort_t Kh[64][72], Kl[64][72];
    __shared__ __align__(16) ushort_t Vh[64][72], Vl[64][72];   // [dd][j]
    __shared__ __align__(16) ushort_t Ph[64][72], Pl[64][72];

    int i0 = blockIdx.x * 64;
    int h0 = blockIdx.y * DK;
    int b  = blockIdx.z;
    const uint* baseH = Hp + (size_t)b * (SS * DD);

    int t = threadIdx.x;
    int w = t >> 6;
    int ln = t & 63;
    int l15 = ln & 15, lh = ln >> 4;

    // stage Q (unpack shifts only)
    {
        int r = t >> 2, cb = (t & 3) << 4;
        const uint* src = &baseH[(size_t)(i0 + r) * DD + h0 + cb];
#pragma unroll
        for (int g = 0; g < 2; g++) {
            U8 qh, ql;
#pragma unroll
            for (int c = 0; c < 2; c++) {
                uint4 pv = *reinterpret_cast<const uint4*>(src + g * 8 + c * 4);
                uint uu[4] = {pv.x, pv.y, pv.z, pv.w};
#pragma unroll
                for (int e = 0; e < 4; e++) {
                    qh.u[c * 4 + e] = (ushort_t)(uu[e] >> 16);
                    ql.u[c * 4 + e] = (ushort_t)(uu[e] & 0xFFFFu);
                }
            }
            *reinterpret_cast<bf16x8*>(&Qh[r][cb + g * 8]) = qh.v;
            *reinterpret_cast<bf16x8*>(&Ql[r][cb + g * 8]) = ql.v;
        }
    }

    float m_[4], l_[4], al[4];
    f32x4 acc[4];
    f32x4 z4 = {0.f, 0.f, 0.f, 0.f};
#pragma unroll
    for (int r = 0; r < 4; r++) { m_[r] = -1e30f; l_[r] = 0.f; acc[r] = z4; }

    for (int j0 = 0; j0 < SS; j0 += 64) {
        __syncthreads();
        // stage K + V(transposed), hi/lo from packed
        {
            int r = t >> 2, cb = (t & 3) << 4;
            const uint* src = &baseH[(size_t)(j0 + r) * DD + h0 + cb];
#pragma unroll
            for (int g = 0; g < 2; g++) {
                U8 kh, kl;
#pragma unroll
                for (int c = 0; c < 2; c++) {
                    uint4 pv = *reinterpret_cast<const uint4*>(src + g * 8 + c * 4);
                    uint uu[4] = {pv.x, pv.y, pv.z, pv.w};
#pragma unroll
                    for (int e = 0; e < 4; e++) {
                        ushort_t hb = (ushort_t)(uu[e] >> 16);
                        ushort_t lb = (ushort_t)(uu[e] & 0xFFFFu);
                        kh.u[c * 4 + e] = hb;
                        kl.u[c * 4 + e] = lb;
                        int d = cb + g * 8 + c * 4 + e;
                        Vh[d][r] = hb;
                        Vl[d][r] = lb;
                    }
                }
                *reinterpret_cast<bf16x8*>(&Kh[r][cb + g * 8]) = kh.v;
                *reinterpret_cast<bf16x8*>(&Kl[r][cb + g * 8]) = kl.v;
            }
        }
        __syncthreads();

        // scores: 3-term split product, scaled by 1/8 post-MFMA
        f32x4 sc[4];
        bf16x8 aqh0 = *reinterpret_cast<const bf16x8*>(&Qh[w * 16 + l15][lh * 8]);
        bf16x8 aqh1 = *reinterpret_cast<const bf16x8*>(&Qh[w * 16 + l15][32 + lh * 8]);
        bf16x8 aql0 = *reinterpret_cast<const bf16x8*>(&Ql[w * 16 + l15][lh * 8]);
        bf16x8 aql1 = *reinterpret_cast<const bf16x8*>(&Ql[w * 16 + l15][32 + lh * 8]);
#pragma unroll
        for (int tt = 0; tt < 4; tt++) {
            bf16x8 bh0 = *reinterpret_cast<const bf16x8*>(&Kh[tt * 16 + l15][lh * 8]);
            bf16x8 bh1 = *reinterpret_cast<const bf16x8*>(&Kh[tt * 16 + l15][32 + lh * 8]);
            bf16x8 bl0 = *reinterpret_cast<const bf16x8*>(&Kl[tt * 16 + l15][lh * 8]);
            bf16x8 bl1 = *reinterpret_cast<const bf16x8*>(&Kl[tt * 16 + l15][32 + lh * 8]);
            f32x4 s = z4;
            s = MFMA(aqh0, bh0, s);
            s = MFMA(aqh1, bh1, s);
            s = MFMA(aqh0, bl0, s);
            s = MFMA(aqh1, bl1, s);
            s = MFMA(aql0, bh0, s);
            s = MFMA(aql1, bh1, s);
            sc[tt] = s * 0.125f;
        }

        // online softmax per row
#pragma unroll
        for (int r = 0; r < 4; r++) {
            float mx = fmaxf(fmaxf(sc[0][r], sc[1][r]), fmaxf(sc[2][r], sc[3][r]));
            mx = fmaxf(mx, __shfl_xor(mx, 1));
            mx = fmaxf(mx, __shfl_xor(mx, 2));
            mx = fmaxf(mx, __shfl_xor(mx, 4));
            mx = fmaxf(mx, __shfl_xor(mx, 8));
            float nm = fmaxf(m_[r], mx);
            al[r] = __expf(m_[r] - nm);
            m_[r] = nm;
            float rs = 0.f;
#pragma unroll
            for (int tt = 0; tt < 4; tt++) {
                float p = __expf(sc[tt][r] - nm);
                sc[tt][r] = p;
                rs += p;
            }
            rs += __shfl_xor(rs, 1);
            rs += __shfl_xor(rs, 2);
            rs += __shfl_xor(rs, 4);
            rs += __shfl_xor(rs, 8);
            l_[r] = l_[r] * al[r] + rs;
        }
        // write P hi/lo (own wave's 16-row band -> within-wave dependence)
#pragma unroll
        for (int tt = 0; tt < 4; tt++)
#pragma unroll
            for (int r = 0; r < 4; r++) {
                ushort_t hb, lb; tsplit(sc[tt][r], hb, lb);
                Ph[w * 16 + lh * 4 + r][tt * 16 + l15] = hb;
                Pl[w * 16 + lh * 4 + r][tt * 16 + l15] = lb;
            }
        // rescale accumulator
#pragma unroll
        for (int td = 0; td < 4; td++) {
            acc[td][0] *= al[0];
            acc[td][1] *= al[1];
            acc[td][2] *= al[2];
            acc[td][3] *= al[3];
        }
        // PV: 3-term split
        bf16x8 aph0 = *reinterpret_cast<const bf16x8*>(&Ph[w * 16 + l15][lh * 8]);
        bf16x8 aph1 = *reinterpret_cast<const bf16x8*>(&Ph[w * 16 + l15][32 + lh * 8]);
        bf16x8 apl0 = *reinterpret_cast<const bf16x8*>(&Pl[w * 16 + l15][lh * 8]);
        bf16x8 apl1 = *reinterpret_cast<const bf16x8*>(&Pl[w * 16 + l15][32 + lh * 8]);
#pragma unroll
        for (int td = 0; td < 4; td++) {
            bf16x8 bvh0 = *reinterpret_cast<const bf16x8*>(&Vh[td * 16 + l15][lh * 8]);
            bf16x8 bvh1 = *reinterpret_cast<const bf16x8*>(&Vh[td * 16 + l15][32 + lh * 8]);
            bf16x8 bvl0 = *reinterpret_cast<const bf16x8*>(&Vl[td * 16 + l15][lh * 8]);
            bf16x8 bvl1 = *reinterpret_cast<const bf16x8*>(&Vl[td * 16 + l15][32 + lh * 8]);
            acc[td] = MFMA(aph0, bvh0, acc[td]);
            acc[td] = MFMA(aph1, bvh1, acc[td]);
            acc[td] = MFMA(aph0, bvl0, acc[td]);
            acc[td] = MFMA(aph1, bvl1, acc[td]);
            acc[td] = MFMA(apl0, bvh0, acc[td]);
            acc[td] = MFMA(apl1, bvh1, acc[td]);
        }
    }

#pragma unroll
    for (int r = 0; r < 4; r++) {
        float inv = 1.f / l_[r];
        int row = i0 + w * 16 + lh * 4 + r;
#pragma unroll
        for (int td = 0; td < 4; td++) {
            float o = acc[td][r] * inv;
            ushort_t hb, lb; tsplit(o, hb, lb);
            size_t idx = (size_t)b * SS * DD + (size_t)row * DD + h0 + td * 16 + l15;
            outh[idx] = hb;
            outl[idx] = lb;
        }
    }
}

// ---------------------------------------------------------------------------
// Kernel 3: C fp32 = A(hi/lo planes [M][K]) @ B(fp32 [K][N]) + bias, 3-term.
// 128x128 tile, BK=64. B transposed+split in LDS, coalesced col-per-thread.
// ---------------------------------------------------------------------------
__global__ __launch_bounds__(256, 2) void gemm_split(const ushort_t* __restrict__ Ah,
                                                     const ushort_t* __restrict__ Al,
                                                     const float* __restrict__ Bsrc,
                                                     const float* __restrict__ bias,
                                                     float* __restrict__ C,
                                                     int M, int N, int K) {
    __shared__ __align__(16) ushort_t Abh[128][72], Abl[128][72];
    __shared__ __align__(16) ushort_t Bbh[128][72], Bbl[128][72];
    int nb = N >> 7;
    int m0 = ((int)blockIdx.x / nb) << 7;
    int n0 = ((int)blockIdx.x % nb) << 7;
    int t = threadIdx.x;
    int w = t >> 6, ln = t & 63, l15 = ln & 15, lh = ln >> 4;
    int wr = (w >> 1) * 64, wc = (w & 1) * 64;

    f32x4 z4 = {0.f, 0.f, 0.f, 0.f};
    f32x4 acc[4][4];
#pragma unroll
    for (int i = 0; i < 4; i++)
#pragma unroll
        for (int j = 0; j < 4; j++) acc[i][j] = z4;

    int arr = t >> 3, akk = (t & 7) * 8;   // A staging: 4 rows x 8 bf16
    int bcol = t & 127, bkb = (t >> 7) * 32;  // B staging: 1 col, 32 k

    for (int k0 = 0; k0 < K; k0 += 64) {
        __syncthreads();
#pragma unroll
        for (int r = 0; r < 4; r++) {
            int row = arr + r * 32;
            *reinterpret_cast<uint4*>(&Abh[row][akk]) =
                *reinterpret_cast<const uint4*>(&Ah[(size_t)(m0 + row) * K + k0 + akk]);
            *reinterpret_cast<uint4*>(&Abl[row][akk]) =
                *reinterpret_cast<const uint4*>(&Al[(size_t)(m0 + row) * K + k0 + akk]);
        }
#pragma unroll
        for (int oct = 0; oct < 4; oct++) {
            U8 ph, pl;
#pragma unroll
            for (int e = 0; e < 8; e++) {
                float f = Bsrc[(size_t)(k0 + bkb + oct * 8 + e) * N + n0 + bcol];
                ushort_t hb, lb; tsplit(f, hb, lb);
                ph.u[e] = hb; pl.u[e] = lb;
            }
            *reinterpret_cast<bf16x8*>(&Bbh[bcol][bkb + oct * 8]) = ph.v;
            *reinterpret_cast<bf16x8*>(&Bbl[bcol][bkb + oct * 8]) = pl.v;
        }
        __syncthreads();
#pragma unroll
        for (int ks = 0; ks < 2; ks++) {
            bf16x8 ah[4], al_[4];
#pragma unroll
            for (int mt = 0; mt < 4; mt++) {
                ah[mt]  = *reinterpret_cast<const bf16x8*>(&Abh[wr + mt * 16 + l15][ks * 32 + lh * 8]);
                al_[mt] = *reinterpret_cast<const bf16x8*>(&Abl[wr + mt * 16 + l15][ks * 32 + lh * 8]);
            }
#pragma unroll
            for (int nt = 0; nt < 4; nt++) {
                bf16x8 bh = *reinterpret_cast<const bf16x8*>(&Bbh[wc + nt * 16 + l15][ks * 32 + lh * 8]);
                bf16x8 bl = *reinterpret_cast<const bf16x8*>(&Bbl[wc + nt * 16 + l15][ks * 32 + lh * 8]);
#pragma unroll
                for (int mt = 0; mt < 4; mt++) {
                    acc[mt][nt] = MFMA(ah[mt], bh, acc[mt][nt]);
                    acc[mt][nt] = MFMA(ah[mt], bl, acc[mt][nt]);
                    acc[mt][nt] = MFMA(al_[mt], bh, acc[mt][nt]);
                }
            }
        }
    }
#pragma unroll
    for (int nt = 0; nt < 4; nt++) {
        int col = n0 + wc + nt * 16 + l15;
        float bs = bias[col];
#pragma unroll
        for (int mt = 0; mt < 4; mt++)
#pragma unroll
            for (int r = 0; r < 4; r++)
                C[(size_t)(m0 + wr + mt * 16 + lh * 4 + r) * N + col] = acc[mt][nt][r] + bs;
    }
}

// ---------------------------------------------------------------------------
// Kernel 4: Hp = pack(layernorm(unpack(Hp) + add) * g + b)
// ---------------------------------------------------------------------------
__global__ __launch_bounds__(256) void ln_residual(uint* __restrict__ Hp,
                                                   const float* __restrict__ add,
                                                   const float* __restrict__ g,
                                                   const float* __restrict__ bta) {
    int row = blockIdx.x * 4 + (threadIdx.x >> 6);
    int lane = threadIdx.x & 63;
    uint* hp = Hp + (size_t)row * DD;
    const float* ap = add + (size_t)row * DD;
    float v[8];
    float sum = 0.f;
#pragma unroll
    for (int i = 0; i < 8; i++) {
        int d = lane + i * 64;
        v[i] = unpackf(hp[d]) + ap[d];
        sum += v[i];
    }
#pragma unroll
    for (int off = 32; off > 0; off >>= 1) sum += __shfl_xor(sum, off);
    float mu = sum * (1.f / DD);
    float s2 = 0.f;
#pragma unroll
    for (int i = 0; i < 8; i++) {
        float d2 = v[i] - mu;
        s2 += d2 * d2;
    }
#pragma unroll
    for (int off = 32; off > 0; off >>= 1) s2 += __shfl_xor(s2, off);
    float inv = rsqrtf(s2 * (1.f / DD) + 1e-5f);
#pragma unroll
    for (int i = 0; i < 8; i++) {
        int d = lane + i * 64;
        hp[d] = packsplit((v[i] - mu) * inv * g[d] + bta[d]);
    }
}

// ---------------------------------------------------------------------------
// Kernel 5: fused FFN, 128m x 256n tile, BK=32, 3-term MFMA.
// A2 = relu(qout@W1+b1) generated in-block (2 n-blocks -> half the dup of r3).
// ---------------------------------------------------------------------------
__global__ __launch_bounds__(256, 2) void ffn_split(const uint* __restrict__ Hp,
                                                    const float* __restrict__ W1,
                                                    const float* __restrict__ b1,
                                                    const float* __restrict__ W2,
                                                    const float* __restrict__ b2,
                                                    const float* __restrict__ theta,
                                                    float* __restrict__ outp) {
    __shared__ __align__(16) ushort_t Abh[128][40], Abl[128][40];
    __shared__ __align__(16) ushort_t Bbh[256][40], Bbl[256][40];
    __shared__ __align__(16) float qs[128][12];
    __shared__ float tcs[8];

    int t = threadIdx.x;
    int m0 = (int)(blockIdx.x >> 1) * 128;
    int n0 = (int)(blockIdx.x & 1) * 256;
    if (t < 8) tcs[t] = cosf(theta[t]);
    __syncthreads();
#pragma unroll
    for (int i = 0; i < 4; i++) {
        int idx = t + i * 256;
        int m = idx >> 3, n = idx & 7;
        qs[m][n] = cosf(unpackf(Hp[(size_t)(m0 + m) * DD + n])) * tcs[n];
    }

    int w = t >> 6, ln = t & 63, l15 = ln & 15, lh = ln >> 4;
    int wr = (w >> 1) * 64, wc = (w & 1) * 128;
    f32x4 z4 = {0.f, 0.f, 0.f, 0.f};
    f32x4 acc[4][8];
#pragma unroll
    for (int i = 0; i < 4; i++)
#pragma unroll
        for (int j = 0; j < 8; j++) acc[i][j] = z4;

    int kk = t & 31, mg = (t >> 5) * 16;    // A2 gen: 1 k, 16 rows

    for (int k0 = 0; k0 < FF; k0 += 32) {
        __syncthreads();
        // A2 panel: relu(qs @ W1 + b1) -> hi/lo
        float w1v[8];
#pragma unroll
        for (int n = 0; n < 8; n++) w1v[n] = W1[n * FF + k0 + kk];
        float b1v = b1[k0 + kk];
#pragma unroll 4
        for (int i = 0; i < 16; i++) {
            int m = mg + i;
            float4 q0 = *reinterpret_cast<const float4*>(&qs[m][0]);
            float4 q1 = *reinterpret_cast<const float4*>(&qs[m][4]);
            float v = b1v;
            v = fmaf(q0.x, w1v[0], v);
            v = fmaf(q0.y, w1v[1], v);
            v = fmaf(q0.z, w1v[2], v);
            v = fmaf(q0.w, w1v[3], v);
            v = fmaf(q1.x, w1v[4], v);
            v = fmaf(q1.y, w1v[5], v);
            v = fmaf(q1.z, w1v[6], v);
            v = fmaf(q1.w, w1v[7], v);
            v = fmaxf(v, 0.f);
            ushort_t hb, lb; tsplit(v, hb, lb);
            Abh[m][kk] = hb;
            Abl[m][kk] = lb;
        }
        // B panel: W2 fp32 [FF][DD] -> transposed hi/lo, col-per-thread (coalesced)
#pragma unroll
        for (int oct = 0; oct < 4; oct++) {
            U8 ph, pl;
#pragma unroll
            for (int e = 0; e < 8; e++) {
                float f = W2[(size_t)(k0 + oct * 8 + e) * DD + n0 + t];
                ushort_t hb, lb; tsplit(f, hb, lb);
                ph.u[e] = hb; pl.u[e] = lb;
            }
            *reinterpret_cast<bf16x8*>(&Bbh[t][oct * 8]) = ph.v;
            *reinterpret_cast<bf16x8*>(&Bbl[t][oct * 8]) = pl.v;
        }
        __syncthreads();
        bf16x8 ah[4], al_[4];
#pragma unroll
        for (int mt = 0; mt < 4; mt++) {
            ah[mt]  = *reinterpret_cast<const bf16x8*>(&Abh[wr + mt * 16 + l15][lh * 8]);
            al_[mt] = *reinterpret_cast<const bf16x8*>(&Abl[wr + mt * 16 + l15][lh * 8]);
        }
#pragma unroll
        for (int nt = 0; nt < 8; nt++) {
            bf16x8 bh = *reinterpret_cast<const bf16x8*>(&Bbh[wc + nt * 16 + l15][lh * 8]);
            bf16x8 bl = *reinterpret_cast<const bf16x8*>(&Bbl[wc + nt * 16 + l15][lh * 8]);
#pragma unroll
            for (int mt = 0; mt < 4; mt++) {
                acc[mt][nt] = MFMA(ah[mt], bh, acc[mt][nt]);
                acc[mt][nt] = MFMA(ah[mt], bl, acc[mt][nt]);
                acc[mt][nt] = MFMA(al_[mt], bh, acc[mt][nt]);
            }
        }
    }
#pragma unroll
    for (int nt = 0; nt < 8; nt++) {
        int col = n0 + wc + nt * 16 + l15;
        float bs = b2[col];
#pragma unroll
        for (int mt = 0; mt < 4; mt++)
#pragma unroll
            for (int r = 0; r < 4; r++)
                outp[(size_t)(m0 + wr + mt * 16 + lh * 4 + r) * DD + col] = acc[mt][nt][r] + bs;
    }
}

// ---------------------------------------------------------------------------
// Kernel 6: pooled[b,d] = mean_s h[b,s,d]
// ---------------------------------------------------------------------------
__global__ __launch_bounds__(256) void pool_mean(const uint* __restrict__ Hp,
                                                 float* __restrict__ pooled) {
    int idx = blockIdx.x * 256 + threadIdx.x;
    if (idx >= BB * DD) return;
    int b = idx >> 9, d = idx & 511;
    float s = 0.f;
    for (int j = 0; j < SS; j++) s += unpackf(Hp[((size_t)b * SS + j) * DD + d]);
    pooled[idx] = s * (1.f / SS);
}

// ---------------------------------------------------------------------------
// Kernel 7: out[b,c] = pooled[b,:] . clf_w[:,c] + clf_b[c]
// ---------------------------------------------------------------------------
__global__ __launch_bounds__(64) void classifier(const float* __restrict__ pooled,
                                                 const float* __restrict__ W,
                                                 const float* __restrict__ bias,
                                                 float* __restrict__ out) {
    int o = blockIdx.x;
    int b = o / CC, c = o % CC;
    int lane = threadIdx.x;
    float s = 0.f;
    for (int d = lane; d < DD; d += 64) s += pooled[b * DD + d] * W[d * CC + c];
#pragma unroll
    for (int off = 32; off > 0; off >>= 1) s += __shfl_xor(s, off);
    if (lane == 0) out[o] = s + bias[c];
}

// ---------------------------------------------------------------------------
extern "C" void kernel_launch(void* const* d_in, const int* in_sizes, int n_in,
                              void* d_out, int out_size, void* d_ws, size_t ws_size,
                              hipStream_t stream) {
    (void)in_sizes; (void)n_in; (void)out_size; (void)ws_size;
    const int*   x      = (const int*)d_in[0];
    const float* emb    = (const float*)d_in[1];
    const float* ln1_g  = (const float*)d_in[2];
    const float* ln1_b  = (const float*)d_in[3];
    const float* ln2_g  = (const float*)d_in[4];
    const float* ln2_b  = (const float*)d_in[5];
    const float* attn_w = (const float*)d_in[6];
    const float* attn_b = (const float*)d_in[7];
    const float* theta  = (const float*)d_in[8];
    const float* ffn_w1 = (const float*)d_in[9];
    const float* ffn_b1 = (const float*)d_in[10];
    const float* ffn_w2 = (const float*)d_in[11];
    const float* ffn_b2 = (const float*)d_in[12];
    const float* clf_w  = (const float*)d_in[13];
    const float* clf_b  = (const float*)d_in[14];
    float* out = (float*)d_out;

    char* ws = (char*)d_ws;
    uint*     Hp     = (uint*)(ws);                     // 32 MB packed hi|lo
    float*    t2     = (float*)(ws + 33554432);         // 32 MB fp32
    ushort_t* t1h    = (ushort_t*)(ws + 67108864);      // 16 MB bf16 hi
    ushort_t* t1l    = (ushort_t*)(ws + 83886080);      // 16 MB bf16 lo
    float*    pooled = (float*)(ws + 100663296);        // 64 KB

    embed_pe<<<(BB * SS * DD + 255) / 256, 256, 0, stream>>>(x, emb, Hp);

    for (int l = 0; l < LL; l++) {
        flash_attn_split<<<dim3(SS / 64, HH, BB), 256, 0, stream>>>(Hp, t1h, t1l);
        gemm_split<<<(16384 / 128) * (DD / 128), 256, 0, stream>>>(
            t1h, t1l, attn_w + (size_t)l * DD * DD, attn_b + l * DD, t2, BB * SS, DD, DD);
        ln_residual<<<BB * SS / 4, 256, 0, stream>>>(Hp, t2, ln1_g + l * DD, ln1_b + l * DD);
        ffn_split<<<(16384 / 128) * 2, 256, 0, stream>>>(
            Hp, ffn_w1 + (size_t)l * NQ * FF, ffn_b1 + l * FF,
            ffn_w2 + (size_t)l * FF * DD, ffn_b2 + l * DD, theta + l * NQ, t2);
        ln_residual<<<BB * SS / 4, 256, 0, stream>>>(Hp, t2, ln2_g + l * DD, ln2_b + l * DD);
    }

    pool_mean<<<(BB * DD + 255) / 256, 256, 0, stream>>>(Hp, pooled);
    classifier<<<BB * CC, 64, 0, stream>>>(pooled, clf_w, clf_b, out);
}

// Round 6
// 2431.720 us; speedup vs baseline: 3.7755x; 1.1009x over previous
//
#include <hip/hip_runtime.h>
#include <hip/hip_bf16.h>
#include <math.h>

#define BB 32
#define SS 512
#define DD 512
#define HH 8
#define DK 64
#define LL 6
#define NQ 8
#define FF 2048
#define CC 10

typedef unsigned int uint;
typedef unsigned short ushort_t;
using bf16x8 = __attribute__((ext_vector_type(8))) short;
using f32x4  = __attribute__((ext_vector_type(4))) float;

#define MFMA(a, b, c) __builtin_amdgcn_mfma_f32_16x16x32_bf16((a), (b), (c), 0, 0, 0)

union U8 { ushort_t u[8]; bf16x8 v; };

__device__ inline ushort_t f2bf(float x) {           // fp32 -> bf16, RNE
    uint u = __float_as_uint(x);
    u += 0x7FFFu + ((u >> 16) & 1u);
    return (ushort_t)(u >> 16);
}
// truncation split: hi = top 16 bits, lo = RNE(residual); hi+lo = v to ~2^-17 rel
__device__ inline void tsplit(float v, ushort_t& hi, ushort_t& lo) {
    uint u = __float_as_uint(v);
    hi = (ushort_t)(u >> 16);
    lo = f2bf(v - __uint_as_float(u & 0xFFFF0000u));
}
__device__ inline uint packsplit(float v) {
    uint u = __float_as_uint(v) & 0xFFFF0000u;
    uint ru = __float_as_uint(v - __uint_as_float(u));
    ru += 0x7FFFu + ((ru >> 16) & 1u);
    return u | (ru >> 16);
}
__device__ inline float unpackf(uint u) {
    return __uint_as_float(u & 0xFFFF0000u) + __uint_as_float(u << 16);
}

// ---------------------------------------------------------------------------
// Kernel 1: h[b,s,d] = emb[x[b,s], d] + pe(s,d), stored packed hi|lo bf16
// ---------------------------------------------------------------------------
__global__ __launch_bounds__(256) void embed_pe(const int* __restrict__ x,
                                                const float* __restrict__ emb,
                                                uint* __restrict__ Hp) {
    int idx = blockIdx.x * 256 + threadIdx.x;
    if (idx >= BB * SS * DD) return;
    int d = idx & (DD - 1);
    int s = (idx >> 9) & (SS - 1);
    int tok = x[idx >> 9];
    int i2 = d >> 1;
    float freq = expf((float)(2 * i2) * (-9.210340371976184f / (float)DD));
    float ang = (float)s * freq;
    float pe = (d & 1) ? cosf(ang) : sinf(ang);
    Hp[idx] = packsplit(emb[(size_t)tok * DD + d] + pe);
}

// ---------------------------------------------------------------------------
// Kernel 1b: transpose + split fp32 [K][N] -> bf16 hi/lo [N][K]  (weight prep)
// ---------------------------------------------------------------------------
__global__ __launch_bounds__(256) void transpose_split_w(const float* __restrict__ in,
                                                         ushort_t* __restrict__ outh,
                                                         ushort_t* __restrict__ outl,
                                                         int K, int N) {
    __shared__ ushort_t th[64][68], tl[64][68];
    int nb = N >> 6;
    int k0 = ((int)blockIdx.x / nb) << 6;
    int n0 = ((int)blockIdx.x % nb) << 6;
    int t = threadIdx.x;
    int r = t >> 2, cb = (t & 3) << 4;
#pragma unroll
    for (int c = 0; c < 4; c++) {
        float4 v = *reinterpret_cast<const float4*>(&in[(size_t)(k0 + r) * N + n0 + cb + 4 * c]);
        float vv[4] = {v.x, v.y, v.z, v.w};
#pragma unroll
        for (int e = 0; e < 4; e++) {
            ushort_t hb, lb; tsplit(vv[e], hb, lb);
            th[r][cb + 4 * c + e] = hb;
            tl[r][cb + 4 * c + e] = lb;
        }
    }
    __syncthreads();
    int n = t >> 2, kb = (t & 3) << 4;
#pragma unroll
    for (int c = 0; c < 4; c++) {
        ushort4 oh, ol;
        oh.x = th[kb + 4 * c + 0][n]; ol.x = tl[kb + 4 * c + 0][n];
        oh.y = th[kb + 4 * c + 1][n]; ol.y = tl[kb + 4 * c + 1][n];
        oh.z = th[kb + 4 * c + 2][n]; ol.z = tl[kb + 4 * c + 2][n];
        oh.w = th[kb + 4 * c + 3][n]; ol.w = tl[kb + 4 * c + 3][n];
        *reinterpret_cast<ushort4*>(&outh[(size_t)(n0 + n) * K + k0 + kb + 4 * c]) = oh;
        *reinterpret_cast<ushort4*>(&outl[(size_t)(n0 + n) * K + k0 + kb + 4 * c]) = ol;
    }
}

// ---------------------------------------------------------------------------
// Kernel 2: split-precision MFMA flash attention on packed h.
// grid (S/64, H, B), 4 waves; every matmul = 3-term bf16 hi/lo product.
// ---------------------------------------------------------------------------
__global__ __launch_bounds__(256, 2) void flash_attn_split(const uint* __restrict__ Hp,
                                                           ushort_t* __restrict__ outh,
                                                           ushort_t* __restrict__ outl) {
    __shared__ __align__(16) ushort_t Qh[64][72], Ql[64][72];
    __shared__ __align__(16) ushort_t Kh[64][72], Kl[64][72];
    __shared__ __align__(16) ushort_t Vh[64][72], Vl[64][72];   // [dd][j]
    __shared__ __align__(16) ushort_t Ph[64][72], Pl[64][72];

    int i0 = blockIdx.x * 64;
    int h0 = blockIdx.y * DK;
    int b  = blockIdx.z;
    const uint* baseH = Hp + (size_t)b * (SS * DD);

    int t = threadIdx.x;
    int w = t >> 6;
    int ln = t & 63;
    int l15 = ln & 15, lh = ln >> 4;

    // stage Q (unpack shifts only)
    {
        int r = t >> 2, cb = (t & 3) << 4;
        const uint* src = &baseH[(size_t)(i0 + r) * DD + h0 + cb];
#pragma unroll
        for (int g = 0; g < 2; g++) {
            U8 qh, ql;
#pragma unroll
            for (int c = 0; c < 2; c++) {
                uint4 pv = *reinterpret_cast<const uint4*>(src + g * 8 + c * 4);
                uint uu[4] = {pv.x, pv.y, pv.z, pv.w};
#pragma unroll
                for (int e = 0; e < 4; e++) {
                    qh.u[c * 4 + e] = (ushort_t)(uu[e] >> 16);
                    ql.u[c * 4 + e] = (ushort_t)(uu[e] & 0xFFFFu);
                }
            }
            *reinterpret_cast<bf16x8*>(&Qh[r][cb + g * 8]) = qh.v;
            *reinterpret_cast<bf16x8*>(&Ql[r][cb + g * 8]) = ql.v;
        }
    }

    float m_[4], l_[4], al[4];
    f32x4 acc[4];
    f32x4 z4 = {0.f, 0.f, 0.f, 0.f};
#pragma unroll
    for (int r = 0; r < 4; r++) { m_[r] = -1e30f; l_[r] = 0.f; acc[r] = z4; }

    for (int j0 = 0; j0 < SS; j0 += 64) {
        __syncthreads();
        // stage K + V(transposed), hi/lo from packed
        {
            int r = t >> 2, cb = (t & 3) << 4;
            const uint* src = &baseH[(size_t)(j0 + r) * DD + h0 + cb];
#pragma unroll
            for (int g = 0; g < 2; g++) {
                U8 kh, kl;
#pragma unroll
                for (int c = 0; c < 2; c++) {
                    uint4 pv = *reinterpret_cast<const uint4*>(src + g * 8 + c * 4);
                    uint uu[4] = {pv.x, pv.y, pv.z, pv.w};
#pragma unroll
                    for (int e = 0; e < 4; e++) {
                        ushort_t hb = (ushort_t)(uu[e] >> 16);
                        ushort_t lb = (ushort_t)(uu[e] & 0xFFFFu);
                        kh.u[c * 4 + e] = hb;
                        kl.u[c * 4 + e] = lb;
                        int d = cb + g * 8 + c * 4 + e;
                        Vh[d][r] = hb;
                        Vl[d][r] = lb;
                    }
                }
                *reinterpret_cast<bf16x8*>(&Kh[r][cb + g * 8]) = kh.v;
                *reinterpret_cast<bf16x8*>(&Kl[r][cb + g * 8]) = kl.v;
            }
        }
        __syncthreads();

        // scores: 3-term split product, scaled by 1/8 post-MFMA
        f32x4 sc[4];
        bf16x8 aqh0 = *reinterpret_cast<const bf16x8*>(&Qh[w * 16 + l15][lh * 8]);
        bf16x8 aqh1 = *reinterpret_cast<const bf16x8*>(&Qh[w * 16 + l15][32 + lh * 8]);
        bf16x8 aql0 = *reinterpret_cast<const bf16x8*>(&Ql[w * 16 + l15][lh * 8]);
        bf16x8 aql1 = *reinterpret_cast<const bf16x8*>(&Ql[w * 16 + l15][32 + lh * 8]);
#pragma unroll
        for (int tt = 0; tt < 4; tt++) {
            bf16x8 bh0 = *reinterpret_cast<const bf16x8*>(&Kh[tt * 16 + l15][lh * 8]);
            bf16x8 bh1 = *reinterpret_cast<const bf16x8*>(&Kh[tt * 16 + l15][32 + lh * 8]);
            bf16x8 bl0 = *reinterpret_cast<const bf16x8*>(&Kl[tt * 16 + l15][lh * 8]);
            bf16x8 bl1 = *reinterpret_cast<const bf16x8*>(&Kl[tt * 16 + l15][32 + lh * 8]);
            f32x4 s = z4;
            s = MFMA(aqh0, bh0, s);
            s = MFMA(aqh1, bh1, s);
            s = MFMA(aqh0, bl0, s);
            s = MFMA(aqh1, bl1, s);
            s = MFMA(aql0, bh0, s);
            s = MFMA(aql1, bh1, s);
            sc[tt] = s * 0.125f;
        }

        // online softmax per row
#pragma unroll
        for (int r = 0; r < 4; r++) {
            float mx = fmaxf(fmaxf(sc[0][r], sc[1][r]), fmaxf(sc[2][r], sc[3][r]));
            mx = fmaxf(mx, __shfl_xor(mx, 1));
            mx = fmaxf(mx, __shfl_xor(mx, 2));
            mx = fmaxf(mx, __shfl_xor(mx, 4));
            mx = fmaxf(mx, __shfl_xor(mx, 8));
            float nm = fmaxf(m_[r], mx);
            al[r] = __expf(m_[r] - nm);
            m_[r] = nm;
            float rs = 0.f;
#pragma unroll
            for (int tt = 0; tt < 4; tt++) {
                float p = __expf(sc[tt][r] - nm);
                sc[tt][r] = p;
                rs += p;
            }
            rs += __shfl_xor(rs, 1);
            rs += __shfl_xor(rs, 2);
            rs += __shfl_xor(rs, 4);
            rs += __shfl_xor(rs, 8);
            l_[r] = l_[r] * al[r] + rs;
        }
        // write P hi/lo (own wave's 16-row band -> within-wave dependence)
#pragma unroll
        for (int tt = 0; tt < 4; tt++)
#pragma unroll
            for (int r = 0; r < 4; r++) {
                ushort_t hb, lb; tsplit(sc[tt][r], hb, lb);
                Ph[w * 16 + lh * 4 + r][tt * 16 + l15] = hb;
                Pl[w * 16 + lh * 4 + r][tt * 16 + l15] = lb;
            }
        // rescale accumulator
#pragma unroll
        for (int td = 0; td < 4; td++) {
            acc[td][0] *= al[0];
            acc[td][1] *= al[1];
            acc[td][2] *= al[2];
            acc[td][3] *= al[3];
        }
        // PV: 3-term split
        bf16x8 aph0 = *reinterpret_cast<const bf16x8*>(&Ph[w * 16 + l15][lh * 8]);
        bf16x8 aph1 = *reinterpret_cast<const bf16x8*>(&Ph[w * 16 + l15][32 + lh * 8]);
        bf16x8 apl0 = *reinterpret_cast<const bf16x8*>(&Pl[w * 16 + l15][lh * 8]);
        bf16x8 apl1 = *reinterpret_cast<const bf16x8*>(&Pl[w * 16 + l15][32 + lh * 8]);
#pragma unroll
        for (int td = 0; td < 4; td++) {
            bf16x8 bvh0 = *reinterpret_cast<const bf16x8*>(&Vh[td * 16 + l15][lh * 8]);
            bf16x8 bvh1 = *reinterpret_cast<const bf16x8*>(&Vh[td * 16 + l15][32 + lh * 8]);
            bf16x8 bvl0 = *reinterpret_cast<const bf16x8*>(&Vl[td * 16 + l15][lh * 8]);
            bf16x8 bvl1 = *reinterpret_cast<const bf16x8*>(&Vl[td * 16 + l15][32 + lh * 8]);
            acc[td] = MFMA(aph0, bvh0, acc[td]);
            acc[td] = MFMA(aph1, bvh1, acc[td]);
            acc[td] = MFMA(aph0, bvl0, acc[td]);
            acc[td] = MFMA(aph1, bvl1, acc[td]);
            acc[td] = MFMA(apl0, bvh0, acc[td]);
            acc[td] = MFMA(apl1, bvh1, acc[td]);
        }
    }

#pragma unroll
    for (int r = 0; r < 4; r++) {
        float inv = 1.f / l_[r];
        int row = i0 + w * 16 + lh * 4 + r;
#pragma unroll
        for (int td = 0; td < 4; td++) {
            float o = acc[td][r] * inv;
            ushort_t hb, lb; tsplit(o, hb, lb);
            size_t idx = (size_t)b * SS * DD + (size_t)row * DD + h0 + td * 16 + l15;
            outh[idx] = hb;
            outl[idx] = lb;
        }
    }
}

// ---------------------------------------------------------------------------
// Kernel 3: C fp32 = A(hi/lo planes [M][K]) @ B(fp32 [K][N]) + bias, 3-term.
// 128x128 tile, BK=64. B transposed+split in LDS, coalesced col-per-thread.
// ---------------------------------------------------------------------------
__global__ __launch_bounds__(256, 2) void gemm_split(const ushort_t* __restrict__ Ah,
                                                     const ushort_t* __restrict__ Al,
                                                     const float* __restrict__ Bsrc,
                                                     const float* __restrict__ bias,
                                                     float* __restrict__ C,
                                                     int M, int N, int K) {
    __shared__ __align__(16) ushort_t Abh[128][72], Abl[128][72];
    __shared__ __align__(16) ushort_t Bbh[128][72], Bbl[128][72];
    int nb = N >> 7;
    int m0 = ((int)blockIdx.x / nb) << 7;
    int n0 = ((int)blockIdx.x % nb) << 7;
    int t = threadIdx.x;
    int w = t >> 6, ln = t & 63, l15 = ln & 15, lh = ln >> 4;
    int wr = (w >> 1) * 64, wc = (w & 1) * 64;

    f32x4 z4 = {0.f, 0.f, 0.f, 0.f};
    f32x4 acc[4][4];
#pragma unroll
    for (int i = 0; i < 4; i++)
#pragma unroll
        for (int j = 0; j < 4; j++) acc[i][j] = z4;

    int arr = t >> 3, akk = (t & 7) * 8;   // A staging: 4 rows x 8 bf16
    int bcol = t & 127, bkb = (t >> 7) * 32;  // B staging: 1 col, 32 k

    for (int k0 = 0; k0 < K; k0 += 64) {
        __syncthreads();
#pragma unroll
        for (int r = 0; r < 4; r++) {
            int row = arr + r * 32;
            *reinterpret_cast<uint4*>(&Abh[row][akk]) =
                *reinterpret_cast<const uint4*>(&Ah[(size_t)(m0 + row) * K + k0 + akk]);
            *reinterpret_cast<uint4*>(&Abl[row][akk]) =
                *reinterpret_cast<const uint4*>(&Al[(size_t)(m0 + row) * K + k0 + akk]);
        }
#pragma unroll
        for (int oct = 0; oct < 4; oct++) {
            U8 ph, pl;
#pragma unroll
            for (int e = 0; e < 8; e++) {
                float f = Bsrc[(size_t)(k0 + bkb + oct * 8 + e) * N + n0 + bcol];
                ushort_t hb, lb; tsplit(f, hb, lb);
                ph.u[e] = hb; pl.u[e] = lb;
            }
            *reinterpret_cast<bf16x8*>(&Bbh[bcol][bkb + oct * 8]) = ph.v;
            *reinterpret_cast<bf16x8*>(&Bbl[bcol][bkb + oct * 8]) = pl.v;
        }
        __syncthreads();
#pragma unroll
        for (int ks = 0; ks < 2; ks++) {
            bf16x8 ah[4], al_[4];
#pragma unroll
            for (int mt = 0; mt < 4; mt++) {
                ah[mt]  = *reinterpret_cast<const bf16x8*>(&Abh[wr + mt * 16 + l15][ks * 32 + lh * 8]);
                al_[mt] = *reinterpret_cast<const bf16x8*>(&Abl[wr + mt * 16 + l15][ks * 32 + lh * 8]);
            }
#pragma unroll
            for (int nt = 0; nt < 4; nt++) {
                bf16x8 bh = *reinterpret_cast<const bf16x8*>(&Bbh[wc + nt * 16 + l15][ks * 32 + lh * 8]);
                bf16x8 bl = *reinterpret_cast<const bf16x8*>(&Bbl[wc + nt * 16 + l15][ks * 32 + lh * 8]);
#pragma unroll
                for (int mt = 0; mt < 4; mt++) {
                    acc[mt][nt] = MFMA(ah[mt], bh, acc[mt][nt]);
                    acc[mt][nt] = MFMA(ah[mt], bl, acc[mt][nt]);
                    acc[mt][nt] = MFMA(al_[mt], bh, acc[mt][nt]);
                }
            }
        }
    }
#pragma unroll
    for (int nt = 0; nt < 4; nt++) {
        int col = n0 + wc + nt * 16 + l15;
        float bs = bias[col];
#pragma unroll
        for (int mt = 0; mt < 4; mt++)
#pragma unroll
            for (int r = 0; r < 4; r++)
                C[(size_t)(m0 + wr + mt * 16 + lh * 4 + r) * N + col] = acc[mt][nt][r] + bs;
    }
}

// ---------------------------------------------------------------------------
// Kernel 4: Hp = pack(layernorm(unpack(Hp) + add) * g + b)
// ---------------------------------------------------------------------------
__global__ __launch_bounds__(256) void ln_residual(uint* __restrict__ Hp,
                                                   const float* __restrict__ add,
                                                   const float* __restrict__ g,
                                                   const float* __restrict__ bta) {
    int row = blockIdx.x * 4 + (threadIdx.x >> 6);
    int lane = threadIdx.x & 63;
    uint* hp = Hp + (size_t)row * DD;
    const float* ap = add + (size_t)row * DD;
    float v[8];
    float sum = 0.f;
#pragma unroll
    for (int i = 0; i < 8; i++) {
        int d = lane + i * 64;
        v[i] = unpackf(hp[d]) + ap[d];
        sum += v[i];
    }
#pragma unroll
    for (int off = 32; off > 0; off >>= 1) sum += __shfl_xor(sum, off);
    float mu = sum * (1.f / DD);
    float s2 = 0.f;
#pragma unroll
    for (int i = 0; i < 8; i++) {
        float d2 = v[i] - mu;
        s2 += d2 * d2;
    }
#pragma unroll
    for (int off = 32; off > 0; off >>= 1) s2 += __shfl_xor(s2, off);
    float inv = rsqrtf(s2 * (1.f / DD) + 1e-5f);
#pragma unroll
    for (int i = 0; i < 8; i++) {
        int d = lane + i * 64;
        hp[d] = packsplit((v[i] - mu) * inv * g[d] + bta[d]);
    }
}

// ---------------------------------------------------------------------------
// Kernel 5: fused FFN, 128m x 128n tile, BK=64, grid 512 (2 blocks/CU).
// A2 = relu(qout@W1+b1) generated in-block; B staged from PRE-SPLIT W2 planes
// (pure uint4 copies, zero VALU).
// ---------------------------------------------------------------------------
__global__ __launch_bounds__(256, 2) void ffn_split(const uint* __restrict__ Hp,
                                                    const float* __restrict__ W1,
                                                    const float* __restrict__ b1,
                                                    const ushort_t* __restrict__ W2th,
                                                    const ushort_t* __restrict__ W2tl,
                                                    const float* __restrict__ b2,
                                                    const float* __restrict__ theta,
                                                    float* __restrict__ outp) {
    __shared__ __align__(16) ushort_t Abh[128][72], Abl[128][72];
    __shared__ __align__(16) ushort_t Bbh[128][72], Bbl[128][72];
    __shared__ __align__(16) float qs[128][12];
    __shared__ float tcs[8];

    int t = threadIdx.x;
    int m0 = (int)(blockIdx.x >> 2) * 128;
    int n0 = (int)(blockIdx.x & 3) * 128;
    if (t < 8) tcs[t] = cosf(theta[t]);
    __syncthreads();
#pragma unroll
    for (int i = 0; i < 4; i++) {
        int idx = t + i * 256;
        int m = idx >> 3, n = idx & 7;
        qs[m][n] = cosf(unpackf(Hp[(size_t)(m0 + m) * DD + n])) * tcs[n];
    }

    int w = t >> 6, ln = t & 63, l15 = ln & 15, lh = ln >> 4;
    int wr = (w >> 1) * 64, wc = (w & 1) * 64;
    f32x4 z4 = {0.f, 0.f, 0.f, 0.f};
    f32x4 acc[4][4];
#pragma unroll
    for (int i = 0; i < 4; i++)
#pragma unroll
        for (int j = 0; j < 4; j++) acc[i][j] = z4;

    int kk = t & 63, mg = (t >> 6) * 32;     // A2 gen: 1 k, 32 rows
    int brr = t >> 3, bkk = (t & 7) * 8;     // B stage: 4 rows x 8 bf16

    for (int k0 = 0; k0 < FF; k0 += 64) {
        __syncthreads();
        // A2 panel: relu(qs @ W1 + b1) -> hi/lo
        float w1v[8];
#pragma unroll
        for (int n = 0; n < 8; n++) w1v[n] = W1[n * FF + k0 + kk];
        float b1v = b1[k0 + kk];
#pragma unroll 4
        for (int i = 0; i < 32; i++) {
            int m = mg + i;
            float4 q0 = *reinterpret_cast<const float4*>(&qs[m][0]);
            float4 q1 = *reinterpret_cast<const float4*>(&qs[m][4]);
            float v = b1v;
            v = fmaf(q0.x, w1v[0], v);
            v = fmaf(q0.y, w1v[1], v);
            v = fmaf(q0.z, w1v[2], v);
            v = fmaf(q0.w, w1v[3], v);
            v = fmaf(q1.x, w1v[4], v);
            v = fmaf(q1.y, w1v[5], v);
            v = fmaf(q1.z, w1v[6], v);
            v = fmaf(q1.w, w1v[7], v);
            v = fmaxf(v, 0.f);
            ushort_t hb, lb; tsplit(v, hb, lb);
            Abh[m][kk] = hb;
            Abl[m][kk] = lb;
        }
        // B panel: pre-split transposed W2 -> pure vector copies
#pragma unroll
        for (int r = 0; r < 4; r++) {
            int row = brr + r * 32;
            *reinterpret_cast<uint4*>(&Bbh[row][bkk]) =
                *reinterpret_cast<const uint4*>(&W2th[(size_t)(n0 + row) * FF + k0 + bkk]);
            *reinterpret_cast<uint4*>(&Bbl[row][bkk]) =
                *reinterpret_cast<const uint4*>(&W2tl[(size_t)(n0 + row) * FF + k0 + bkk]);
        }
        __syncthreads();
#pragma unroll
        for (int ks = 0; ks < 2; ks++) {
            bf16x8 ah[4], al_[4];
#pragma unroll
            for (int mt = 0; mt < 4; mt++) {
                ah[mt]  = *reinterpret_cast<const bf16x8*>(&Abh[wr + mt * 16 + l15][ks * 32 + lh * 8]);
                al_[mt] = *reinterpret_cast<const bf16x8*>(&Abl[wr + mt * 16 + l15][ks * 32 + lh * 8]);
            }
#pragma unroll
            for (int nt = 0; nt < 4; nt++) {
                bf16x8 bh = *reinterpret_cast<const bf16x8*>(&Bbh[wc + nt * 16 + l15][ks * 32 + lh * 8]);
                bf16x8 bl = *reinterpret_cast<const bf16x8*>(&Bbl[wc + nt * 16 + l15][ks * 32 + lh * 8]);
#pragma unroll
                for (int mt = 0; mt < 4; mt++) {
                    acc[mt][nt] = MFMA(ah[mt], bh, acc[mt][nt]);
                    acc[mt][nt] = MFMA(ah[mt], bl, acc[mt][nt]);
                    acc[mt][nt] = MFMA(al_[mt], bh, acc[mt][nt]);
                }
            }
        }
    }
#pragma unroll
    for (int nt = 0; nt < 4; nt++) {
        int col = n0 + wc + nt * 16 + l15;
        float bs = b2[col];
#pragma unroll
        for (int mt = 0; mt < 4; mt++)
#pragma unroll
            for (int r = 0; r < 4; r++)
                outp[(size_t)(m0 + wr + mt * 16 + lh * 4 + r) * DD + col] = acc[mt][nt][r] + bs;
    }
}

// ---------------------------------------------------------------------------
// Kernel 6: pooled[b,d] = mean_s h[b,s,d]
// ---------------------------------------------------------------------------
__global__ __launch_bounds__(256) void pool_mean(const uint* __restrict__ Hp,
                                                 float* __restrict__ pooled) {
    int idx = blockIdx.x * 256 + threadIdx.x;
    if (idx >= BB * DD) return;
    int b = idx >> 9, d = idx & 511;
    float s = 0.f;
    for (int j = 0; j < SS; j++) s += unpackf(Hp[((size_t)b * SS + j) * DD + d]);
    pooled[idx] = s * (1.f / SS);
}

// ---------------------------------------------------------------------------
// Kernel 7: out[b,c] = pooled[b,:] . clf_w[:,c] + clf_b[c]
// ---------------------------------------------------------------------------
__global__ __launch_bounds__(64) void classifier(const float* __restrict__ pooled,
                                                 const float* __restrict__ W,
                                                 const float* __restrict__ bias,
                                                 float* __restrict__ out) {
    int o = blockIdx.x;
    int b = o / CC, c = o % CC;
    int lane = threadIdx.x;
    float s = 0.f;
    for (int d = lane; d < DD; d += 64) s += pooled[b * DD + d] * W[d * CC + c];
#pragma unroll
    for (int off = 32; off > 0; off >>= 1) s += __shfl_xor(s, off);
    if (lane == 0) out[o] = s + bias[c];
}

// ---------------------------------------------------------------------------
extern "C" void kernel_launch(void* const* d_in, const int* in_sizes, int n_in,
                              void* d_out, int out_size, void* d_ws, size_t ws_size,
                              hipStream_t stream) {
    (void)in_sizes; (void)n_in; (void)out_size; (void)ws_size;
    const int*   x      = (const int*)d_in[0];
    const float* emb    = (const float*)d_in[1];
    const float* ln1_g  = (const float*)d_in[2];
    const float* ln1_b  = (const float*)d_in[3];
    const float* ln2_g  = (const float*)d_in[4];
    const float* ln2_b  = (const float*)d_in[5];
    const float* attn_w = (const float*)d_in[6];
    const float* attn_b = (const float*)d_in[7];
    const float* theta  = (const float*)d_in[8];
    const float* ffn_w1 = (const float*)d_in[9];
    const float* ffn_b1 = (const float*)d_in[10];
    const float* ffn_w2 = (const float*)d_in[11];
    const float* ffn_b2 = (const float*)d_in[12];
    const float* clf_w  = (const float*)d_in[13];
    const float* clf_b  = (const float*)d_in[14];
    float* out = (float*)d_out;

    char* ws = (char*)d_ws;
    uint*     Hp     = (uint*)(ws);                     // 32 MB packed hi|lo
    float*    t2     = (float*)(ws + 33554432);         // 32 MB fp32
    ushort_t* t1h    = (ushort_t*)(ws + 67108864);      // 16 MB bf16 hi
    ushort_t* t1l    = (ushort_t*)(ws + 83886080);      // 16 MB bf16 lo
    float*    pooled = (float*)(ws + 100663296);        // 64 KB
    // W2 pre-split planes live in the t1h region (dead between gemm and the
    // next layer's flash): [DD][FF] hi at +0, lo at +2MB.
    ushort_t* W2th   = (ushort_t*)(ws + 67108864);
    ushort_t* W2tl   = (ushort_t*)(ws + 67108864 + 2097152);

    embed_pe<<<(BB * SS * DD + 255) / 256, 256, 0, stream>>>(x, emb, Hp);

    for (int l = 0; l < LL; l++) {
        flash_attn_split<<<dim3(SS / 64, HH, BB), 256, 0, stream>>>(Hp, t1h, t1l);
        gemm_split<<<(16384 / 128) * (DD / 128), 256, 0, stream>>>(
            t1h, t1l, attn_w + (size_t)l * DD * DD, attn_b + l * DD, t2, BB * SS, DD, DD);
        ln_residual<<<BB * SS / 4, 256, 0, stream>>>(Hp, t2, ln1_g + l * DD, ln1_b + l * DD);
        transpose_split_w<<<(FF / 64) * (DD / 64), 256, 0, stream>>>(
            ffn_w2 + (size_t)l * FF * DD, W2th, W2tl, FF, DD);
        ffn_split<<<(16384 / 128) * (DD / 128), 256, 0, stream>>>(
            Hp, ffn_w1 + (size_t)l * NQ * FF, ffn_b1 + l * FF,
            W2th, W2tl, ffn_b2 + l * DD, theta + l * NQ, t2);
        ln_residual<<<BB * SS / 4, 256, 0, stream>>>(Hp, t2, ln2_g + l * DD, ln2_b + l * DD);
    }

    pool_mean<<<(BB * DD + 255) / 256, 256, 0, stream>>>(Hp, pooled);
    classifier<<<BB * CC, 64, 0, stream>>>(pooled, clf_w, clf_b, out);
}

// Round 7
// 2021.720 us; speedup vs baseline: 4.5411x; 1.2028x over previous
//
#include <hip/hip_runtime.h>
#include <hip/hip_bf16.h>
#include <math.h>

#define BB 32
#define SS 512
#define DD 512
#define HH 8
#define DK 64
#define LL 6
#define NQ 8
#define FF 2048
#define CC 10

typedef unsigned int uint;
typedef unsigned short ushort_t;
using bf16x8 = __attribute__((ext_vector_type(8))) short;
using f32x4  = __attribute__((ext_vector_type(4))) float;

#define MFMA(a, b, c) __builtin_amdgcn_mfma_f32_16x16x32_bf16((a), (b), (c), 0, 0, 0)

union U8 { ushort_t u[8]; bf16x8 v; };

__device__ inline ushort_t f2bf(float x) {           // fp32 -> bf16, RNE
    uint u = __float_as_uint(x);
    u += 0x7FFFu + ((u >> 16) & 1u);
    return (ushort_t)(u >> 16);
}
// truncation split: hi = top 16 bits, lo = RNE(residual); hi+lo = v to ~2^-17 rel
__device__ inline void tsplit(float v, ushort_t& hi, ushort_t& lo) {
    uint u = __float_as_uint(v);
    hi = (ushort_t)(u >> 16);
    lo = f2bf(v - __uint_as_float(u & 0xFFFF0000u));
}
// cheap variant (lo also truncated, ~2^-16): used on A2 only
__device__ inline void tsplit_fast(float v, ushort_t& hi, ushort_t& lo) {
    uint u = __float_as_uint(v);
    hi = (ushort_t)(u >> 16);
    float res = v - __uint_as_float(u & 0xFFFF0000u);
    lo = (ushort_t)(__float_as_uint(res) >> 16);
}
__device__ inline uint packsplit(float v) {
    uint u = __float_as_uint(v) & 0xFFFF0000u;
    uint ru = __float_as_uint(v - __uint_as_float(u));
    ru += 0x7FFFu + ((ru >> 16) & 1u);
    return u | (ru >> 16);
}
__device__ inline float unpackf(uint u) {
    return __uint_as_float(u & 0xFFFF0000u) + __uint_as_float(u << 16);
}

// ---------------------------------------------------------------------------
// Kernel 1: h[b,s,d] = emb[x[b,s], d] + pe(s,d), stored packed hi|lo bf16
// ---------------------------------------------------------------------------
__global__ __launch_bounds__(256) void embed_pe(const int* __restrict__ x,
                                                const float* __restrict__ emb,
                                                uint* __restrict__ Hp) {
    int idx = blockIdx.x * 256 + threadIdx.x;
    if (idx >= BB * SS * DD) return;
    int d = idx & (DD - 1);
    int s = (idx >> 9) & (SS - 1);
    int tok = x[idx >> 9];
    int i2 = d >> 1;
    float freq = expf((float)(2 * i2) * (-9.210340371976184f / (float)DD));
    float ang = (float)s * freq;
    float pe = (d & 1) ? cosf(ang) : sinf(ang);
    Hp[idx] = packsplit(emb[(size_t)tok * DD + d] + pe);
}

// ---------------------------------------------------------------------------
// Kernel 1b: transpose + split fp32 [K][N] -> bf16 hi/lo [N][K]  (weight prep)
// ---------------------------------------------------------------------------
__global__ __launch_bounds__(256) void transpose_split_w(const float* __restrict__ in,
                                                         ushort_t* __restrict__ outh,
                                                         ushort_t* __restrict__ outl,
                                                         int K, int N) {
    __shared__ ushort_t th[64][68], tl[64][68];
    int nb = N >> 6;
    int k0 = ((int)blockIdx.x / nb) << 6;
    int n0 = ((int)blockIdx.x % nb) << 6;
    int t = threadIdx.x;
    int r = t >> 2, cb = (t & 3) << 4;
#pragma unroll
    for (int c = 0; c < 4; c++) {
        float4 v = *reinterpret_cast<const float4*>(&in[(size_t)(k0 + r) * N + n0 + cb + 4 * c]);
        float vv[4] = {v.x, v.y, v.z, v.w};
#pragma unroll
        for (int e = 0; e < 4; e++) {
            ushort_t hb, lb; tsplit(vv[e], hb, lb);
            th[r][cb + 4 * c + e] = hb;
            tl[r][cb + 4 * c + e] = lb;
        }
    }
    __syncthreads();
    int n = t >> 2, kb = (t & 3) << 4;
#pragma unroll
    for (int c = 0; c < 4; c++) {
        ushort4 oh, ol;
        oh.x = th[kb + 4 * c + 0][n]; ol.x = tl[kb + 4 * c + 0][n];
        oh.y = th[kb + 4 * c + 1][n]; ol.y = tl[kb + 4 * c + 1][n];
        oh.z = th[kb + 4 * c + 2][n]; ol.z = tl[kb + 4 * c + 2][n];
        oh.w = th[kb + 4 * c + 3][n]; ol.w = tl[kb + 4 * c + 3][n];
        *reinterpret_cast<ushort4*>(&outh[(size_t)(n0 + n) * K + k0 + kb + 4 * c]) = oh;
        *reinterpret_cast<ushort4*>(&outl[(size_t)(n0 + n) * K + k0 + kb + 4 * c]) = ol;
    }
}

// ---------------------------------------------------------------------------
// Kernel 1c: W1 [L][8][FF] -> transposed split planes [L][FF][8] bf16 hi/lo
// ---------------------------------------------------------------------------
__global__ __launch_bounds__(256) void prep_w1t(const float* __restrict__ W1all,
                                                ushort_t* __restrict__ outh,
                                                ushort_t* __restrict__ outl) {
    int l = blockIdx.y;
    int f = blockIdx.x * 256 + threadIdx.x;
    const float* W1 = W1all + (size_t)l * NQ * FF;
    U8 ph, pl;
#pragma unroll
    for (int n = 0; n < 8; n++) {
        ushort_t hb, lb; tsplit(W1[n * FF + f], hb, lb);
        ph.u[n] = hb; pl.u[n] = lb;
    }
    *reinterpret_cast<bf16x8*>(&outh[((size_t)l * FF + f) * 8]) = ph.v;
    *reinterpret_cast<bf16x8*>(&outl[((size_t)l * FF + f) * 8]) = pl.v;
}

// ---------------------------------------------------------------------------
// Kernel 2: split-precision MFMA flash attention on packed h.  (unchanged)
// ---------------------------------------------------------------------------
__global__ __launch_bounds__(256, 2) void flash_attn_split(const uint* __restrict__ Hp,
                                                           ushort_t* __restrict__ outh,
                                                           ushort_t* __restrict__ outl) {
    __shared__ __align__(16) ushort_t Qh[64][72], Ql[64][72];
    __shared__ __align__(16) ushort_t Kh[64][72], Kl[64][72];
    __shared__ __align__(16) ushort_t Vh[64][72], Vl[64][72];   // [dd][j]
    __shared__ __align__(16) ushort_t Ph[64][72], Pl[64][72];

    int i0 = blockIdx.x * 64;
    int h0 = blockIdx.y * DK;
    int b  = blockIdx.z;
    const uint* baseH = Hp + (size_t)b * (SS * DD);

    int t = threadIdx.x;
    int w = t >> 6;
    int ln = t & 63;
    int l15 = ln & 15, lh = ln >> 4;

    {
        int r = t >> 2, cb = (t & 3) << 4;
        const uint* src = &baseH[(size_t)(i0 + r) * DD + h0 + cb];
#pragma unroll
        for (int g = 0; g < 2; g++) {
            U8 qh, ql;
#pragma unroll
            for (int c = 0; c < 2; c++) {
                uint4 pv = *reinterpret_cast<const uint4*>(src + g * 8 + c * 4);
                uint uu[4] = {pv.x, pv.y, pv.z, pv.w};
#pragma unroll
                for (int e = 0; e < 4; e++) {
                    qh.u[c * 4 + e] = (ushort_t)(uu[e] >> 16);
                    ql.u[c * 4 + e] = (ushort_t)(uu[e] & 0xFFFFu);
                }
            }
            *reinterpret_cast<bf16x8*>(&Qh[r][cb + g * 8]) = qh.v;
            *reinterpret_cast<bf16x8*>(&Ql[r][cb + g * 8]) = ql.v;
        }
    }

    float m_[4], l_[4], al[4];
    f32x4 acc[4];
    f32x4 z4 = {0.f, 0.f, 0.f, 0.f};
#pragma unroll
    for (int r = 0; r < 4; r++) { m_[r] = -1e30f; l_[r] = 0.f; acc[r] = z4; }

    for (int j0 = 0; j0 < SS; j0 += 64) {
        __syncthreads();
        {
            int r = t >> 2, cb = (t & 3) << 4;
            const uint* src = &baseH[(size_t)(j0 + r) * DD + h0 + cb];
#pragma unroll
            for (int g = 0; g < 2; g++) {
                U8 kh, kl;
#pragma unroll
                for (int c = 0; c < 2; c++) {
                    uint4 pv = *reinterpret_cast<const uint4*>(src + g * 8 + c * 4);
                    uint uu[4] = {pv.x, pv.y, pv.z, pv.w};
#pragma unroll
                    for (int e = 0; e < 4; e++) {
                        ushort_t hb = (ushort_t)(uu[e] >> 16);
                        ushort_t lb = (ushort_t)(uu[e] & 0xFFFFu);
                        kh.u[c * 4 + e] = hb;
                        kl.u[c * 4 + e] = lb;
                        int d = cb + g * 8 + c * 4 + e;
                        Vh[d][r] = hb;
                        Vl[d][r] = lb;
                    }
                }
                *reinterpret_cast<bf16x8*>(&Kh[r][cb + g * 8]) = kh.v;
                *reinterpret_cast<bf16x8*>(&Kl[r][cb + g * 8]) = kl.v;
            }
        }
        __syncthreads();

        f32x4 sc[4];
        bf16x8 aqh0 = *reinterpret_cast<const bf16x8*>(&Qh[w * 16 + l15][lh * 8]);
        bf16x8 aqh1 = *reinterpret_cast<const bf16x8*>(&Qh[w * 16 + l15][32 + lh * 8]);
        bf16x8 aql0 = *reinterpret_cast<const bf16x8*>(&Ql[w * 16 + l15][lh * 8]);
        bf16x8 aql1 = *reinterpret_cast<const bf16x8*>(&Ql[w * 16 + l15][32 + lh * 8]);
#pragma unroll
        for (int tt = 0; tt < 4; tt++) {
            bf16x8 bh0 = *reinterpret_cast<const bf16x8*>(&Kh[tt * 16 + l15][lh * 8]);
            bf16x8 bh1 = *reinterpret_cast<const bf16x8*>(&Kh[tt * 16 + l15][32 + lh * 8]);
            bf16x8 bl0 = *reinterpret_cast<const bf16x8*>(&Kl[tt * 16 + l15][lh * 8]);
            bf16x8 bl1 = *reinterpret_cast<const bf16x8*>(&Kl[tt * 16 + l15][32 + lh * 8]);
            f32x4 s = z4;
            s = MFMA(aqh0, bh0, s);
            s = MFMA(aqh1, bh1, s);
            s = MFMA(aqh0, bl0, s);
            s = MFMA(aqh1, bl1, s);
            s = MFMA(aql0, bh0, s);
            s = MFMA(aql1, bh1, s);
            sc[tt] = s * 0.125f;
        }

#pragma unroll
        for (int r = 0; r < 4; r++) {
            float mx = fmaxf(fmaxf(sc[0][r], sc[1][r]), fmaxf(sc[2][r], sc[3][r]));
            mx = fmaxf(mx, __shfl_xor(mx, 1));
            mx = fmaxf(mx, __shfl_xor(mx, 2));
            mx = fmaxf(mx, __shfl_xor(mx, 4));
            mx = fmaxf(mx, __shfl_xor(mx, 8));
            float nm = fmaxf(m_[r], mx);
            al[r] = __expf(m_[r] - nm);
            m_[r] = nm;
            float rs = 0.f;
#pragma unroll
            for (int tt = 0; tt < 4; tt++) {
                float p = __expf(sc[tt][r] - nm);
                sc[tt][r] = p;
                rs += p;
            }
            rs += __shfl_xor(rs, 1);
            rs += __shfl_xor(rs, 2);
            rs += __shfl_xor(rs, 4);
            rs += __shfl_xor(rs, 8);
            l_[r] = l_[r] * al[r] + rs;
        }
#pragma unroll
        for (int tt = 0; tt < 4; tt++)
#pragma unroll
            for (int r = 0; r < 4; r++) {
                ushort_t hb, lb; tsplit(sc[tt][r], hb, lb);
                Ph[w * 16 + lh * 4 + r][tt * 16 + l15] = hb;
                Pl[w * 16 + lh * 4 + r][tt * 16 + l15] = lb;
            }
#pragma unroll
        for (int td = 0; td < 4; td++) {
            acc[td][0] *= al[0];
            acc[td][1] *= al[1];
            acc[td][2] *= al[2];
            acc[td][3] *= al[3];
        }
        bf16x8 aph0 = *reinterpret_cast<const bf16x8*>(&Ph[w * 16 + l15][lh * 8]);
        bf16x8 aph1 = *reinterpret_cast<const bf16x8*>(&Ph[w * 16 + l15][32 + lh * 8]);
        bf16x8 apl0 = *reinterpret_cast<const bf16x8*>(&Pl[w * 16 + l15][lh * 8]);
        bf16x8 apl1 = *reinterpret_cast<const bf16x8*>(&Pl[w * 16 + l15][32 + lh * 8]);
#pragma unroll
        for (int td = 0; td < 4; td++) {
            bf16x8 bvh0 = *reinterpret_cast<const bf16x8*>(&Vh[td * 16 + l15][lh * 8]);
            bf16x8 bvh1 = *reinterpret_cast<const bf16x8*>(&Vh[td * 16 + l15][32 + lh * 8]);
            bf16x8 bvl0 = *reinterpret_cast<const bf16x8*>(&Vl[td * 16 + l15][lh * 8]);
            bf16x8 bvl1 = *reinterpret_cast<const bf16x8*>(&Vl[td * 16 + l15][32 + lh * 8]);
            acc[td] = MFMA(aph0, bvh0, acc[td]);
            acc[td] = MFMA(aph1, bvh1, acc[td]);
            acc[td] = MFMA(aph0, bvl0, acc[td]);
            acc[td] = MFMA(aph1, bvl1, acc[td]);
            acc[td] = MFMA(apl0, bvh0, acc[td]);
            acc[td] = MFMA(apl1, bvh1, acc[td]);
        }
    }

#pragma unroll
    for (int r = 0; r < 4; r++) {
        float inv = 1.f / l_[r];
        int row = i0 + w * 16 + lh * 4 + r;
#pragma unroll
        for (int td = 0; td < 4; td++) {
            float o = acc[td][r] * inv;
            ushort_t hb, lb; tsplit(o, hb, lb);
            size_t idx = (size_t)b * SS * DD + (size_t)row * DD + h0 + td * 16 + l15;
            outh[idx] = hb;
            outl[idx] = lb;
        }
    }
}

// ---------------------------------------------------------------------------
// Kernel 3: C fp32 = A(hi/lo [M][K]) @ Bt(pre-split hi/lo [N][K]) + bias.
// 128x128 tile, BK=64. All staging = pure uint4 copies.
// ---------------------------------------------------------------------------
__global__ __launch_bounds__(256, 2) void gemm_split(const ushort_t* __restrict__ Ah,
                                                     const ushort_t* __restrict__ Al,
                                                     const ushort_t* __restrict__ Bth,
                                                     const ushort_t* __restrict__ Btl,
                                                     const float* __restrict__ bias,
                                                     float* __restrict__ C,
                                                     int M, int N, int K) {
    __shared__ __align__(16) ushort_t Abh[128][72], Abl[128][72];
    __shared__ __align__(16) ushort_t Bbh[128][72], Bbl[128][72];
    int nb = N >> 7;
    int m0 = ((int)blockIdx.x / nb) << 7;
    int n0 = ((int)blockIdx.x % nb) << 7;
    int t = threadIdx.x;
    int w = t >> 6, ln = t & 63, l15 = ln & 15, lh = ln >> 4;
    int wr = (w >> 1) * 64, wc = (w & 1) * 64;

    f32x4 z4 = {0.f, 0.f, 0.f, 0.f};
    f32x4 acc[4][4];
#pragma unroll
    for (int i = 0; i < 4; i++)
#pragma unroll
        for (int j = 0; j < 4; j++) acc[i][j] = z4;

    int arr = t >> 3, akk = (t & 7) * 8;

    for (int k0 = 0; k0 < K; k0 += 64) {
        __syncthreads();
#pragma unroll
        for (int r = 0; r < 4; r++) {
            int row = arr + r * 32;
            *reinterpret_cast<uint4*>(&Abh[row][akk]) =
                *reinterpret_cast<const uint4*>(&Ah[(size_t)(m0 + row) * K + k0 + akk]);
            *reinterpret_cast<uint4*>(&Abl[row][akk]) =
                *reinterpret_cast<const uint4*>(&Al[(size_t)(m0 + row) * K + k0 + akk]);
            *reinterpret_cast<uint4*>(&Bbh[row][akk]) =
                *reinterpret_cast<const uint4*>(&Bth[(size_t)(n0 + row) * K + k0 + akk]);
            *reinterpret_cast<uint4*>(&Bbl[row][akk]) =
                *reinterpret_cast<const uint4*>(&Btl[(size_t)(n0 + row) * K + k0 + akk]);
        }
        __syncthreads();
#pragma unroll
        for (int ks = 0; ks < 2; ks++) {
            bf16x8 ah[4], al_[4];
#pragma unroll
            for (int mt = 0; mt < 4; mt++) {
                ah[mt]  = *reinterpret_cast<const bf16x8*>(&Abh[wr + mt * 16 + l15][ks * 32 + lh * 8]);
                al_[mt] = *reinterpret_cast<const bf16x8*>(&Abl[wr + mt * 16 + l15][ks * 32 + lh * 8]);
            }
#pragma unroll
            for (int nt = 0; nt < 4; nt++) {
                bf16x8 bh = *reinterpret_cast<const bf16x8*>(&Bbh[wc + nt * 16 + l15][ks * 32 + lh * 8]);
                bf16x8 bl = *reinterpret_cast<const bf16x8*>(&Bbl[wc + nt * 16 + l15][ks * 32 + lh * 8]);
#pragma unroll
                for (int mt = 0; mt < 4; mt++) {
                    acc[mt][nt] = MFMA(ah[mt], bh, acc[mt][nt]);
                    acc[mt][nt] = MFMA(ah[mt], bl, acc[mt][nt]);
                    acc[mt][nt] = MFMA(al_[mt], bh, acc[mt][nt]);
                }
            }
        }
    }
#pragma unroll
    for (int nt = 0; nt < 4; nt++) {
        int col = n0 + wc + nt * 16 + l15;
        float bs = bias[col];
#pragma unroll
        for (int mt = 0; mt < 4; mt++)
#pragma unroll
            for (int r = 0; r < 4; r++)
                C[(size_t)(m0 + wr + mt * 16 + lh * 4 + r) * N + col] = acc[mt][nt][r] + bs;
    }
}

// ---------------------------------------------------------------------------
// Kernel 4: Hp = pack(layernorm(unpack(Hp) + add) * g + b)   (unchanged)
// ---------------------------------------------------------------------------
__global__ __launch_bounds__(256) void ln_residual(uint* __restrict__ Hp,
                                                   const float* __restrict__ add,
                                                   const float* __restrict__ g,
                                                   const float* __restrict__ bta) {
    int row = blockIdx.x * 4 + (threadIdx.x >> 6);
    int lane = threadIdx.x & 63;
    uint* hp = Hp + (size_t)row * DD;
    const float* ap = add + (size_t)row * DD;
    float v[8];
    float sum = 0.f;
#pragma unroll
    for (int i = 0; i < 8; i++) {
        int d = lane + i * 64;
        v[i] = unpackf(hp[d]) + ap[d];
        sum += v[i];
    }
#pragma unroll
    for (int off = 32; off > 0; off >>= 1) sum += __shfl_xor(sum, off);
    float mu = sum * (1.f / DD);
    float s2 = 0.f;
#pragma unroll
    for (int i = 0; i < 8; i++) {
        float d2 = v[i] - mu;
        s2 += d2 * d2;
    }
#pragma unroll
    for (int off = 32; off > 0; off >>= 1) s2 += __shfl_xor(s2, off);
    float inv = rsqrtf(s2 * (1.f / DD) + 1e-5f);
#pragma unroll
    for (int i = 0; i < 8; i++) {
        int d = lane + i * 64;
        hp[d] = packsplit((v[i] - mu) * inv * g[d] + bta[d]);
    }
}

// ---------------------------------------------------------------------------
// Kernel 5: fused FFN, 128x128 tile, BK=64. A2 = relu(qout@W1+b1) computed
// ON THE MATRIX PIPE (K=8 padded to 32 via zeroed lanes), written to LDS as
// packed b64 hi/lo. B staged from pre-split W2 planes (pure uint4 copies).
// ---------------------------------------------------------------------------
__global__ __launch_bounds__(256, 2) void ffn_split(const uint* __restrict__ Hp,
                                                    const ushort_t* __restrict__ W1th,
                                                    const ushort_t* __restrict__ W1tl,
                                                    const float* __restrict__ b1,
                                                    const ushort_t* __restrict__ W2th,
                                                    const ushort_t* __restrict__ W2tl,
                                                    const float* __restrict__ b2,
                                                    const float* __restrict__ theta,
                                                    float* __restrict__ outp) {
    __shared__ __align__(16) ushort_t Abh[128][72], Abl[128][72];
    __shared__ __align__(16) ushort_t Bbh[128][72], Bbl[128][72];
    __shared__ __align__(16) ushort_t qsh[129][8], qsl[129][8];
    __shared__ float tcs[8];

    int t = threadIdx.x;
    int m0 = (int)(blockIdx.x >> 2) * 128;
    int n0 = (int)(blockIdx.x & 3) * 128;
    if (t < 8) {
        tcs[t] = cosf(theta[t]);
        qsh[128][t] = 0;         // zero row for lh!=0 B-frag reads
        qsl[128][t] = 0;
    }
    __syncthreads();
    // stage qs split: qout[m][n] = cos(h)*cos(theta), n<8
#pragma unroll
    for (int i = 0; i < 4; i++) {
        int idx = t + i * 256;
        int m = idx >> 3, n = idx & 7;
        float q = cosf(unpackf(Hp[(size_t)(m0 + m) * DD + n])) * tcs[n];
        ushort_t hb, lb; tsplit(q, hb, lb);
        qsh[m][n] = hb;
        qsl[m][n] = lb;
    }

    int w = t >> 6, ln = t & 63, l15 = ln & 15, lh = ln >> 4;
    int wr = (w >> 1) * 64, wc = (w & 1) * 64;
    bool lh0 = (lh == 0);
    f32x4 z4 = {0.f, 0.f, 0.f, 0.f};
    bf16x8 z8 = {0, 0, 0, 0, 0, 0, 0, 0};
    f32x4 acc[4][4];
#pragma unroll
    for (int i = 0; i < 4; i++)
#pragma unroll
        for (int j = 0; j < 4; j++) acc[i][j] = z4;

    int brr = t >> 3, bkk = (t & 7) * 8;

    for (int k0 = 0; k0 < FF; k0 += 64) {
        __syncthreads();
        // ---- B stage: pre-split W2 planes, pure vector copies
#pragma unroll
        for (int r = 0; r < 4; r++) {
            int row = brr + r * 32;
            *reinterpret_cast<uint4*>(&Bbh[row][bkk]) =
                *reinterpret_cast<const uint4*>(&W2th[(size_t)(n0 + row) * FF + k0 + bkk]);
            *reinterpret_cast<uint4*>(&Bbl[row][bkk]) =
                *reinterpret_cast<const uint4*>(&W2tl[(size_t)(n0 + row) * FF + k0 + bkk]);
        }
        // ---- A2 via MFMA: D[f][m] = sum_n W1t[f][n]*qs[m][n]
        bf16x8 wh[4], wl[4];
#pragma unroll
        for (int fq = 0; fq < 4; fq++) {
            bf16x8 h8 = *reinterpret_cast<const bf16x8*>(&W1th[(size_t)(k0 + fq * 16 + l15) * 8]);
            bf16x8 l8 = *reinterpret_cast<const bf16x8*>(&W1tl[(size_t)(k0 + fq * 16 + l15) * 8]);
            wh[fq] = lh0 ? h8 : z8;      // lanes lh>0 carry k=8..31 => zero
            wl[fq] = lh0 ? l8 : z8;
        }
#pragma unroll
        for (int mqi = 0; mqi < 2; mqi++) {
            int m = (w * 2 + mqi) * 16 + l15;
            int mrow = lh0 ? m : 128;    // zero row for k=8..31 lanes
            bf16x8 qh  = *reinterpret_cast<const bf16x8*>(&qsh[mrow][0]);
            bf16x8 ql_ = *reinterpret_cast<const bf16x8*>(&qsl[mrow][0]);
#pragma unroll
            for (int fq = 0; fq < 4; fq++) {
                f32x4 d = z4;
                d = MFMA(wh[fq], qh, d);
                d = MFMA(wh[fq], ql_, d);
                d = MFMA(wl[fq], qh, d);
                float4 b1v = *reinterpret_cast<const float4*>(&b1[k0 + fq * 16 + lh * 4]);
                float v0 = fmaxf(d[0] + b1v.x, 0.f);
                float v1 = fmaxf(d[1] + b1v.y, 0.f);
                float v2 = fmaxf(d[2] + b1v.z, 0.f);
                float v3 = fmaxf(d[3] + b1v.w, 0.f);
                ushort_t h0_, l0_, h1_, l1_, h2_, l2_, h3_, l3_;
                tsplit_fast(v0, h0_, l0_);
                tsplit_fast(v1, h1_, l1_);
                tsplit_fast(v2, h2_, l2_);
                tsplit_fast(v3, h3_, l3_);
                uint2 hu, lu;
                hu.x = (uint)h0_ | ((uint)h1_ << 16);
                hu.y = (uint)h2_ | ((uint)h3_ << 16);
                lu.x = (uint)l0_ | ((uint)l1_ << 16);
                lu.y = (uint)l2_ | ((uint)l3_ << 16);
                *reinterpret_cast<uint2*>(&Abh[m][fq * 16 + lh * 4]) = hu;
                *reinterpret_cast<uint2*>(&Abl[m][fq * 16 + lh * 4]) = lu;
            }
        }
        __syncthreads();
        // ---- main GEMM
#pragma unroll
        for (int ks = 0; ks < 2; ks++) {
            bf16x8 ah[4], al_[4];
#pragma unroll
            for (int mt = 0; mt < 4; mt++) {
                ah[mt]  = *reinterpret_cast<const bf16x8*>(&Abh[wr + mt * 16 + l15][ks * 32 + lh * 8]);
                al_[mt] = *reinterpret_cast<const bf16x8*>(&Abl[wr + mt * 16 + l15][ks * 32 + lh * 8]);
            }
#pragma unroll
            for (int nt = 0; nt < 4; nt++) {
                bf16x8 bh = *reinterpret_cast<const bf16x8*>(&Bbh[wc + nt * 16 + l15][ks * 32 + lh * 8]);
                bf16x8 bl = *reinterpret_cast<const bf16x8*>(&Bbl[wc + nt * 16 + l15][ks * 32 + lh * 8]);
#pragma unroll
                for (int mt = 0; mt < 4; mt++) {
                    acc[mt][nt] = MFMA(ah[mt], bh, acc[mt][nt]);
                    acc[mt][nt] = MFMA(ah[mt], bl, acc[mt][nt]);
                    acc[mt][nt] = MFMA(al_[mt], bh, acc[mt][nt]);
                }
            }
        }
    }
#pragma unroll
    for (int nt = 0; nt < 4; nt++) {
        int col = n0 + wc + nt * 16 + l15;
        float bs = b2[col];
#pragma unroll
        for (int mt = 0; mt < 4; mt++)
#pragma unroll
            for (int r = 0; r < 4; r++)
                outp[(size_t)(m0 + wr + mt * 16 + lh * 4 + r) * DD + col] = acc[mt][nt][r] + bs;
    }
}

// ---------------------------------------------------------------------------
// Kernel 6: pooled[b,d] = mean_s h[b,s,d]
// ---------------------------------------------------------------------------
__global__ __launch_bounds__(256) void pool_mean(const uint* __restrict__ Hp,
                                                 float* __restrict__ pooled) {
    int idx = blockIdx.x * 256 + threadIdx.x;
    if (idx >= BB * DD) return;
    int b = idx >> 9, d = idx & 511;
    float s = 0.f;
    for (int j = 0; j < SS; j++) s += unpackf(Hp[((size_t)b * SS + j) * DD + d]);
    pooled[idx] = s * (1.f / SS);
}

// ---------------------------------------------------------------------------
// Kernel 7: out[b,c] = pooled[b,:] . clf_w[:,c] + clf_b[c]
// ---------------------------------------------------------------------------
__global__ __launch_bounds__(64) void classifier(const float* __restrict__ pooled,
                                                 const float* __restrict__ W,
                                                 const float* __restrict__ bias,
                                                 float* __restrict__ out) {
    int o = blockIdx.x;
    int b = o / CC, c = o % CC;
    int lane = threadIdx.x;
    float s = 0.f;
    for (int d = lane; d < DD; d += 64) s += pooled[b * DD + d] * W[d * CC + c];
#pragma unroll
    for (int off = 32; off > 0; off >>= 1) s += __shfl_xor(s, off);
    if (lane == 0) out[o] = s + bias[c];
}

// ---------------------------------------------------------------------------
extern "C" void kernel_launch(void* const* d_in, const int* in_sizes, int n_in,
                              void* d_out, int out_size, void* d_ws, size_t ws_size,
                              hipStream_t stream) {
    (void)in_sizes; (void)n_in; (void)out_size; (void)ws_size;
    const int*   x      = (const int*)d_in[0];
    const float* emb    = (const float*)d_in[1];
    const float* ln1_g  = (const float*)d_in[2];
    const float* ln1_b  = (const float*)d_in[3];
    const float* ln2_g  = (const float*)d_in[4];
    const float* ln2_b  = (const float*)d_in[5];
    const float* attn_w = (const float*)d_in[6];
    const float* attn_b = (const float*)d_in[7];
    const float* theta  = (const float*)d_in[8];
    const float* ffn_w1 = (const float*)d_in[9];
    const float* ffn_b1 = (const float*)d_in[10];
    const float* ffn_w2 = (const float*)d_in[11];
    const float* ffn_b2 = (const float*)d_in[12];
    const float* clf_w  = (const float*)d_in[13];
    const float* clf_b  = (const float*)d_in[14];
    float* out = (float*)d_out;

    char* ws = (char*)d_ws;
    uint*     Hp     = (uint*)(ws);                     // 32 MB packed hi|lo
    float*    t2     = (float*)(ws + 33554432);         // 32 MB fp32
    ushort_t* t1h    = (ushort_t*)(ws + 67108864);      // 16 MB bf16 hi
    ushort_t* t1l    = (ushort_t*)(ws + 83886080);      // 16 MB bf16 lo
    float*    pooled = (float*)(ws + 100663296);        // 64 KB
    ushort_t* Wath   = (ushort_t*)(ws + 100728832);     // 512 KB attn_w hi
    ushort_t* Watl   = (ushort_t*)(ws + 101253120);     // 512 KB attn_w lo
    ushort_t* W1th6  = (ushort_t*)(ws + 101777408);     // 192 KB W1t hi (6 layers)
    ushort_t* W1tl6  = (ushort_t*)(ws + 101974016);     // 192 KB W1t lo
    // W2 planes reuse the t1h region (dead between gemm and next flash)
    ushort_t* W2th   = (ushort_t*)(ws + 67108864);
    ushort_t* W2tl   = (ushort_t*)(ws + 67108864 + 2097152);

    embed_pe<<<(BB * SS * DD + 255) / 256, 256, 0, stream>>>(x, emb, Hp);
    prep_w1t<<<dim3(FF / 256, LL), 256, 0, stream>>>(ffn_w1, W1th6, W1tl6);

    for (int l = 0; l < LL; l++) {
        flash_attn_split<<<dim3(SS / 64, HH, BB), 256, 0, stream>>>(Hp, t1h, t1l);
        transpose_split_w<<<(DD / 64) * (DD / 64), 256, 0, stream>>>(
            attn_w + (size_t)l * DD * DD, Wath, Watl, DD, DD);
        gemm_split<<<(16384 / 128) * (DD / 128), 256, 0, stream>>>(
            t1h, t1l, Wath, Watl, attn_b + l * DD, t2, BB * SS, DD, DD);
        ln_residual<<<BB * SS / 4, 256, 0, stream>>>(Hp, t2, ln1_g + l * DD, ln1_b + l * DD);
        transpose_split_w<<<(FF / 64) * (DD / 64), 256, 0, stream>>>(
            ffn_w2 + (size_t)l * FF * DD, W2th, W2tl, FF, DD);
        ffn_split<<<(16384 / 128) * (DD / 128), 256, 0, stream>>>(
            Hp, W1th6 + (size_t)l * FF * 8, W1tl6 + (size_t)l * FF * 8, ffn_b1 + l * FF,
            W2th, W2tl, ffn_b2 + l * DD, theta + l * NQ, t2);
        ln_residual<<<BB * SS / 4, 256, 0, stream>>>(Hp, t2, ln2_g + l * DD, ln2_b + l * DD);
    }

    pool_mean<<<(BB * DD + 255) / 256, 256, 0, stream>>>(Hp, pooled);
    classifier<<<BB * CC, 64, 0, stream>>>(pooled, clf_w, clf_b, out);
}

// Round 8
// 1867.069 us; speedup vs baseline: 4.9173x; 1.0828x over previous
//
#include <hip/hip_runtime.h>
#include <hip/hip_bf16.h>
#include <math.h>

#define BB 32
#define SS 512
#define DD 512
#define HH 8
#define DK 64
#define LL 6
#define NQ 8
#define FF 2048
#define CC 10

typedef unsigned int uint;
typedef unsigned short ushort_t;
using bf16x8 = __attribute__((ext_vector_type(8))) short;
using f32x4  = __attribute__((ext_vector_type(4))) float;

#define MFMA(a, b, c) __builtin_amdgcn_mfma_f32_16x16x32_bf16((a), (b), (c), 0, 0, 0)

union U8 { ushort_t u[8]; bf16x8 v; };

__device__ inline ushort_t f2bf(float x) {           // fp32 -> bf16, RNE
    uint u = __float_as_uint(x);
    u += 0x7FFFu + ((u >> 16) & 1u);
    return (ushort_t)(u >> 16);
}
// truncation split: hi = top 16 bits, lo = RNE(residual); hi+lo = v to ~2^-17 rel
__device__ inline void tsplit(float v, ushort_t& hi, ushort_t& lo) {
    uint u = __float_as_uint(v);
    hi = (ushort_t)(u >> 16);
    lo = f2bf(v - __uint_as_float(u & 0xFFFF0000u));
}
// cheap variant (lo also truncated, ~2^-16): used on A2 only
__device__ inline void tsplit_fast(float v, ushort_t& hi, ushort_t& lo) {
    uint u = __float_as_uint(v);
    hi = (ushort_t)(u >> 16);
    float res = v - __uint_as_float(u & 0xFFFF0000u);
    lo = (ushort_t)(__float_as_uint(res) >> 16);
}
__device__ inline uint packsplit(float v) {
    uint u = __float_as_uint(v) & 0xFFFF0000u;
    uint ru = __float_as_uint(v - __uint_as_float(u));
    ru += 0x7FFFu + ((ru >> 16) & 1u);
    return u | (ru >> 16);
}
__device__ inline float unpackf(uint u) {
    return __uint_as_float(u & 0xFFFF0000u) + __uint_as_float(u << 16);
}

// ---------------------------------------------------------------------------
// Kernel 1: h[b,s,d] = emb[x[b,s], d] + pe(s,d), stored packed hi|lo bf16
// ---------------------------------------------------------------------------
__global__ __launch_bounds__(256) void embed_pe(const int* __restrict__ x,
                                                const float* __restrict__ emb,
                                                uint* __restrict__ Hp) {
    int idx = blockIdx.x * 256 + threadIdx.x;
    if (idx >= BB * SS * DD) return;
    int d = idx & (DD - 1);
    int s = (idx >> 9) & (SS - 1);
    int tok = x[idx >> 9];
    int i2 = d >> 1;
    float freq = expf((float)(2 * i2) * (-9.210340371976184f / (float)DD));
    float ang = (float)s * freq;
    float pe = (d & 1) ? cosf(ang) : sinf(ang);
    Hp[idx] = packsplit(emb[(size_t)tok * DD + d] + pe);
}

// ---------------------------------------------------------------------------
// Kernel 1b: transpose + split fp32 [K][N] -> bf16 hi/lo [N][K]  (weight prep)
// ---------------------------------------------------------------------------
__global__ __launch_bounds__(256) void transpose_split_w(const float* __restrict__ in,
                                                         ushort_t* __restrict__ outh,
                                                         ushort_t* __restrict__ outl,
                                                         int K, int N) {
    __shared__ ushort_t th[64][68], tl[64][68];
    int nb = N >> 6;
    int k0 = ((int)blockIdx.x / nb) << 6;
    int n0 = ((int)blockIdx.x % nb) << 6;
    int t = threadIdx.x;
    int r = t >> 2, cb = (t & 3) << 4;
#pragma unroll
    for (int c = 0; c < 4; c++) {
        float4 v = *reinterpret_cast<const float4*>(&in[(size_t)(k0 + r) * N + n0 + cb + 4 * c]);
        float vv[4] = {v.x, v.y, v.z, v.w};
#pragma unroll
        for (int e = 0; e < 4; e++) {
            ushort_t hb, lb; tsplit(vv[e], hb, lb);
            th[r][cb + 4 * c + e] = hb;
            tl[r][cb + 4 * c + e] = lb;
        }
    }
    __syncthreads();
    int n = t >> 2, kb = (t & 3) << 4;
#pragma unroll
    for (int c = 0; c < 4; c++) {
        ushort4 oh, ol;
        oh.x = th[kb + 4 * c + 0][n]; ol.x = tl[kb + 4 * c + 0][n];
        oh.y = th[kb + 4 * c + 1][n]; ol.y = tl[kb + 4 * c + 1][n];
        oh.z = th[kb + 4 * c + 2][n]; ol.z = tl[kb + 4 * c + 2][n];
        oh.w = th[kb + 4 * c + 3][n]; ol.w = tl[kb + 4 * c + 3][n];
        *reinterpret_cast<ushort4*>(&outh[(size_t)(n0 + n) * K + k0 + kb + 4 * c]) = oh;
        *reinterpret_cast<ushort4*>(&outl[(size_t)(n0 + n) * K + k0 + kb + 4 * c]) = ol;
    }
}

// ---------------------------------------------------------------------------
// Kernel 1c: W1 [L][8][FF] -> transposed split planes [L][FF][8] bf16 hi/lo
// ---------------------------------------------------------------------------
__global__ __launch_bounds__(256) void prep_w1t(const float* __restrict__ W1all,
                                                ushort_t* __restrict__ outh,
                                                ushort_t* __restrict__ outl) {
    int l = blockIdx.y;
    int f = blockIdx.x * 256 + threadIdx.x;
    const float* W1 = W1all + (size_t)l * NQ * FF;
    U8 ph, pl;
#pragma unroll
    for (int n = 0; n < 8; n++) {
        ushort_t hb, lb; tsplit(W1[n * FF + f], hb, lb);
        ph.u[n] = hb; pl.u[n] = lb;
    }
    *reinterpret_cast<bf16x8*>(&outh[((size_t)l * FF + f) * 8]) = ph.v;
    *reinterpret_cast<bf16x8*>(&outl[((size_t)l * FF + f) * 8]) = pl.v;
}

// ---------------------------------------------------------------------------
// Kernel 2: split-precision MFMA flash attention, QBLK=128, 8 waves.
// Q fragments from global; K staged row-major; V (=K) transposed LDS->LDS
// with conflict-free (c,r) write partition. 3 barriers per KV tile.
// ---------------------------------------------------------------------------
__global__ __launch_bounds__(512, 4) void flash_attn_split(const uint* __restrict__ Hp,
                                                           ushort_t* __restrict__ outh,
                                                           ushort_t* __restrict__ outl) {
    __shared__ __align__(16) ushort_t Kh[64][72], Kl[64][72];
    __shared__ __align__(16) ushort_t Vh[64][72], Vl[64][72];   // [d][j]
    __shared__ __align__(16) ushort_t Ph[128][72], Pl[128][72];

    int i0 = blockIdx.x * 128;
    int h0 = blockIdx.y * DK;
    int b  = blockIdx.z;
    const uint* baseH = Hp + (size_t)b * (SS * DD);

    int t = threadIdx.x;
    int w = t >> 6;          // wave 0..7, owns q-rows i0 + w*16 .. +15
    int ln = t & 63;
    int l15 = ln & 15, lh = ln >> 4;

    // ---- Q fragments straight from global packed h
    bf16x8 aqh0, aqh1, aql0, aql1;
    {
        int row = i0 + w * 16 + l15;
        const uint* src = &baseH[(size_t)row * DD + h0 + lh * 8];
        uint4 p0 = *reinterpret_cast<const uint4*>(src);
        uint4 p1 = *reinterpret_cast<const uint4*>(src + 4);
        uint4 p2 = *reinterpret_cast<const uint4*>(src + 32);
        uint4 p3 = *reinterpret_cast<const uint4*>(src + 36);
        uint a0[8] = {p0.x, p0.y, p0.z, p0.w, p1.x, p1.y, p1.z, p1.w};
        uint a1[8] = {p2.x, p2.y, p2.z, p2.w, p3.x, p3.y, p3.z, p3.w};
        U8 h0u, l0u, h1u, l1u;
#pragma unroll
        for (int e = 0; e < 8; e++) {
            h0u.u[e] = (ushort_t)(a0[e] >> 16);
            l0u.u[e] = (ushort_t)(a0[e] & 0xFFFFu);
            h1u.u[e] = (ushort_t)(a1[e] >> 16);
            l1u.u[e] = (ushort_t)(a1[e] & 0xFFFFu);
        }
        aqh0 = h0u.v; aql0 = l0u.v; aqh1 = h1u.v; aql1 = l1u.v;
    }

    float m_[4], l_[4], al[4];
    f32x4 acc[4];
    f32x4 z4 = {0.f, 0.f, 0.f, 0.f};
#pragma unroll
    for (int r = 0; r < 4; r++) { m_[r] = -1e30f; l_[r] = 0.f; acc[r] = z4; }

    int kr = t >> 3, kcb = (t & 7) * 8;      // K stage: 1 row, 8 cols
    int vc = t & 7, vr = t >> 3;             // V pass: col vc+8e, row vr

    for (int j0 = 0; j0 < SS; j0 += 64) {
        __syncthreads();   // prev PV done with Vh/Ph; prev scores done with Kh
        // ---- stage K row-major (vector writes, hi/lo from packed)
        {
            const uint* src = &baseH[(size_t)(j0 + kr) * DD + h0 + kcb];
            uint4 p0 = *reinterpret_cast<const uint4*>(src);
            uint4 p1 = *reinterpret_cast<const uint4*>(src + 4);
            uint a[8] = {p0.x, p0.y, p0.z, p0.w, p1.x, p1.y, p1.z, p1.w};
            U8 kh, kl;
#pragma unroll
            for (int e = 0; e < 8; e++) {
                kh.u[e] = (ushort_t)(a[e] >> 16);
                kl.u[e] = (ushort_t)(a[e] & 0xFFFFu);
            }
            *reinterpret_cast<bf16x8*>(&Kh[kr][kcb]) = kh.v;
            *reinterpret_cast<bf16x8*>(&Kl[kr][kcb]) = kl.v;
        }
        __syncthreads();   // K ready
        // ---- V pass: transpose K into Vh/Vl (V == K). Conflict-free banks.
#pragma unroll
        for (int e = 0; e < 8; e++) {
            int d = vc + 8 * e;
            Vh[d][vr] = Kh[vr][d];
            Vl[d][vr] = Kl[vr][d];
        }
        // ---- scores: 3-term split product, scaled 1/8 post-MFMA
        f32x4 sc[4];
#pragma unroll
        for (int tt = 0; tt < 4; tt++) {
            bf16x8 bh0 = *reinterpret_cast<const bf16x8*>(&Kh[tt * 16 + l15][lh * 8]);
            bf16x8 bh1 = *reinterpret_cast<const bf16x8*>(&Kh[tt * 16 + l15][32 + lh * 8]);
            bf16x8 bl0 = *reinterpret_cast<const bf16x8*>(&Kl[tt * 16 + l15][lh * 8]);
            bf16x8 bl1 = *reinterpret_cast<const bf16x8*>(&Kl[tt * 16 + l15][32 + lh * 8]);
            f32x4 s = z4;
            s = MFMA(aqh0, bh0, s);
            s = MFMA(aqh1, bh1, s);
            s = MFMA(aqh0, bl0, s);
            s = MFMA(aqh1, bl1, s);
            s = MFMA(aql0, bh0, s);
            s = MFMA(aql1, bh1, s);
            sc[tt] = s * 0.125f;
        }
        // ---- online softmax per row (row = lh*4 + r within wave's 16-band)
#pragma unroll
        for (int r = 0; r < 4; r++) {
            float mx = fmaxf(fmaxf(sc[0][r], sc[1][r]), fmaxf(sc[2][r], sc[3][r]));
            mx = fmaxf(mx, __shfl_xor(mx, 1));
            mx = fmaxf(mx, __shfl_xor(mx, 2));
            mx = fmaxf(mx, __shfl_xor(mx, 4));
            mx = fmaxf(mx, __shfl_xor(mx, 8));
            float nm = fmaxf(m_[r], mx);
            al[r] = __expf(m_[r] - nm);
            m_[r] = nm;
            float rs = 0.f;
#pragma unroll
            for (int tt = 0; tt < 4; tt++) {
                float p = __expf(sc[tt][r] - nm);
                sc[tt][r] = p;
                rs += p;
            }
            rs += __shfl_xor(rs, 1);
            rs += __shfl_xor(rs, 2);
            rs += __shfl_xor(rs, 4);
            rs += __shfl_xor(rs, 8);
            l_[r] = l_[r] * al[r] + rs;
        }
        // ---- write P hi/lo (own wave's 16-row band)
#pragma unroll
        for (int tt = 0; tt < 4; tt++)
#pragma unroll
            for (int r = 0; r < 4; r++) {
                ushort_t hb, lb; tsplit(sc[tt][r], hb, lb);
                Ph[w * 16 + lh * 4 + r][tt * 16 + l15] = hb;
                Pl[w * 16 + lh * 4 + r][tt * 16 + l15] = lb;
            }
        __syncthreads();   // Vh/Vl complete (cross-wave) before PV
        // ---- rescale accumulator
#pragma unroll
        for (int td = 0; td < 4; td++) {
            acc[td][0] *= al[0];
            acc[td][1] *= al[1];
            acc[td][2] *= al[2];
            acc[td][3] *= al[3];
        }
        // ---- PV: 3-term split
        bf16x8 aph0 = *reinterpret_cast<const bf16x8*>(&Ph[w * 16 + l15][lh * 8]);
        bf16x8 aph1 = *reinterpret_cast<const bf16x8*>(&Ph[w * 16 + l15][32 + lh * 8]);
        bf16x8 apl0 = *reinterpret_cast<const bf16x8*>(&Pl[w * 16 + l15][lh * 8]);
        bf16x8 apl1 = *reinterpret_cast<const bf16x8*>(&Pl[w * 16 + l15][32 + lh * 8]);
#pragma unroll
        for (int td = 0; td < 4; td++) {
            bf16x8 bvh0 = *reinterpret_cast<const bf16x8*>(&Vh[td * 16 + l15][lh * 8]);
            bf16x8 bvh1 = *reinterpret_cast<const bf16x8*>(&Vh[td * 16 + l15][32 + lh * 8]);
            bf16x8 bvl0 = *reinterpret_cast<const bf16x8*>(&Vl[td * 16 + l15][lh * 8]);
            bf16x8 bvl1 = *reinterpret_cast<const bf16x8*>(&Vl[td * 16 + l15][32 + lh * 8]);
            acc[td] = MFMA(aph0, bvh0, acc[td]);
            acc[td] = MFMA(aph1, bvh1, acc[td]);
            acc[td] = MFMA(aph0, bvl0, acc[td]);
            acc[td] = MFMA(aph1, bvl1, acc[td]);
            acc[td] = MFMA(apl0, bvh0, acc[td]);
            acc[td] = MFMA(apl1, bvh1, acc[td]);
        }
    }

#pragma unroll
    for (int r = 0; r < 4; r++) {
        float inv = 1.f / l_[r];
        int row = i0 + w * 16 + lh * 4 + r;
#pragma unroll
        for (int td = 0; td < 4; td++) {
            float o = acc[td][r] * inv;
            ushort_t hb, lb; tsplit(o, hb, lb);
            size_t idx = (size_t)b * SS * DD + (size_t)row * DD + h0 + td * 16 + l15;
            outh[idx] = hb;
            outl[idx] = lb;
        }
    }
}

// ---------------------------------------------------------------------------
// Kernel 3: C fp32 = A(hi/lo [M][K]) @ Bt(pre-split hi/lo [N][K]) + bias.
// 128x128 tile, BK=64. All staging = pure uint4 copies.
// ---------------------------------------------------------------------------
__global__ __launch_bounds__(256, 2) void gemm_split(const ushort_t* __restrict__ Ah,
                                                     const ushort_t* __restrict__ Al,
                                                     const ushort_t* __restrict__ Bth,
                                                     const ushort_t* __restrict__ Btl,
                                                     const float* __restrict__ bias,
                                                     float* __restrict__ C,
                                                     int M, int N, int K) {
    __shared__ __align__(16) ushort_t Abh[128][72], Abl[128][72];
    __shared__ __align__(16) ushort_t Bbh[128][72], Bbl[128][72];
    int nb = N >> 7;
    int m0 = ((int)blockIdx.x / nb) << 7;
    int n0 = ((int)blockIdx.x % nb) << 7;
    int t = threadIdx.x;
    int w = t >> 6, ln = t & 63, l15 = ln & 15, lh = ln >> 4;
    int wr = (w >> 1) * 64, wc = (w & 1) * 64;

    f32x4 z4 = {0.f, 0.f, 0.f, 0.f};
    f32x4 acc[4][4];
#pragma unroll
    for (int i = 0; i < 4; i++)
#pragma unroll
        for (int j = 0; j < 4; j++) acc[i][j] = z4;

    int arr = t >> 3, akk = (t & 7) * 8;

    for (int k0 = 0; k0 < K; k0 += 64) {
        __syncthreads();
#pragma unroll
        for (int r = 0; r < 4; r++) {
            int row = arr + r * 32;
            *reinterpret_cast<uint4*>(&Abh[row][akk]) =
                *reinterpret_cast<const uint4*>(&Ah[(size_t)(m0 + row) * K + k0 + akk]);
            *reinterpret_cast<uint4*>(&Abl[row][akk]) =
                *reinterpret_cast<const uint4*>(&Al[(size_t)(m0 + row) * K + k0 + akk]);
            *reinterpret_cast<uint4*>(&Bbh[row][akk]) =
                *reinterpret_cast<const uint4*>(&Bth[(size_t)(n0 + row) * K + k0 + akk]);
            *reinterpret_cast<uint4*>(&Bbl[row][akk]) =
                *reinterpret_cast<const uint4*>(&Btl[(size_t)(n0 + row) * K + k0 + akk]);
        }
        __syncthreads();
#pragma unroll
        for (int ks = 0; ks < 2; ks++) {
            bf16x8 ah[4], al_[4];
#pragma unroll
            for (int mt = 0; mt < 4; mt++) {
                ah[mt]  = *reinterpret_cast<const bf16x8*>(&Abh[wr + mt * 16 + l15][ks * 32 + lh * 8]);
                al_[mt] = *reinterpret_cast<const bf16x8*>(&Abl[wr + mt * 16 + l15][ks * 32 + lh * 8]);
            }
#pragma unroll
            for (int nt = 0; nt < 4; nt++) {
                bf16x8 bh = *reinterpret_cast<const bf16x8*>(&Bbh[wc + nt * 16 + l15][ks * 32 + lh * 8]);
                bf16x8 bl = *reinterpret_cast<const bf16x8*>(&Bbl[wc + nt * 16 + l15][ks * 32 + lh * 8]);
#pragma unroll
                for (int mt = 0; mt < 4; mt++) {
                    acc[mt][nt] = MFMA(ah[mt], bh, acc[mt][nt]);
                    acc[mt][nt] = MFMA(ah[mt], bl, acc[mt][nt]);
                    acc[mt][nt] = MFMA(al_[mt], bh, acc[mt][nt]);
                }
            }
        }
    }
#pragma unroll
    for (int nt = 0; nt < 4; nt++) {
        int col = n0 + wc + nt * 16 + l15;
        float bs = bias[col];
#pragma unroll
        for (int mt = 0; mt < 4; mt++)
#pragma unroll
            for (int r = 0; r < 4; r++)
                C[(size_t)(m0 + wr + mt * 16 + lh * 4 + r) * N + col] = acc[mt][nt][r] + bs;
    }
}

// ---------------------------------------------------------------------------
// Kernel 4: Hp = pack(layernorm(unpack(Hp) + add) * g + b)
// ---------------------------------------------------------------------------
__global__ __launch_bounds__(256) void ln_residual(uint* __restrict__ Hp,
                                                   const float* __restrict__ add,
                                                   const float* __restrict__ g,
                                                   const float* __restrict__ bta) {
    int row = blockIdx.x * 4 + (threadIdx.x >> 6);
    int lane = threadIdx.x & 63;
    uint* hp = Hp + (size_t)row * DD;
    const float* ap = add + (size_t)row * DD;
    float v[8];
    float sum = 0.f;
#pragma unroll
    for (int i = 0; i < 8; i++) {
        int d = lane + i * 64;
        v[i] = unpackf(hp[d]) + ap[d];
        sum += v[i];
    }
#pragma unroll
    for (int off = 32; off > 0; off >>= 1) sum += __shfl_xor(sum, off);
    float mu = sum * (1.f / DD);
    float s2 = 0.f;
#pragma unroll
    for (int i = 0; i < 8; i++) {
        float d2 = v[i] - mu;
        s2 += d2 * d2;
    }
#pragma unroll
    for (int off = 32; off > 0; off >>= 1) s2 += __shfl_xor(s2, off);
    float inv = rsqrtf(s2 * (1.f / DD) + 1e-5f);
#pragma unroll
    for (int i = 0; i < 8; i++) {
        int d = lane + i * 64;
        hp[d] = packsplit((v[i] - mu) * inv * g[d] + bta[d]);
    }
}

// ---------------------------------------------------------------------------
// Kernel 5: fused FFN, 128x128 tile, BK=64. A2 = relu(qout@W1+b1) computed
// ON THE MATRIX PIPE; B staged from pre-split W2 planes.
// ---------------------------------------------------------------------------
__global__ __launch_bounds__(256, 2) void ffn_split(const uint* __restrict__ Hp,
                                                    const ushort_t* __restrict__ W1th,
                                                    const ushort_t* __restrict__ W1tl,
                                                    const float* __restrict__ b1,
                                                    const ushort_t* __restrict__ W2th,
                                                    const ushort_t* __restrict__ W2tl,
                                                    const float* __restrict__ b2,
                                                    const float* __restrict__ theta,
                                                    float* __restrict__ outp) {
    __shared__ __align__(16) ushort_t Abh[128][72], Abl[128][72];
    __shared__ __align__(16) ushort_t Bbh[128][72], Bbl[128][72];
    __shared__ __align__(16) ushort_t qsh[129][8], qsl[129][8];
    __shared__ float tcs[8];

    int t = threadIdx.x;
    int m0 = (int)(blockIdx.x >> 2) * 128;
    int n0 = (int)(blockIdx.x & 3) * 128;
    if (t < 8) {
        tcs[t] = cosf(theta[t]);
        qsh[128][t] = 0;
        qsl[128][t] = 0;
    }
    __syncthreads();
#pragma unroll
    for (int i = 0; i < 4; i++) {
        int idx = t + i * 256;
        int m = idx >> 3, n = idx & 7;
        float q = cosf(unpackf(Hp[(size_t)(m0 + m) * DD + n])) * tcs[n];
        ushort_t hb, lb; tsplit(q, hb, lb);
        qsh[m][n] = hb;
        qsl[m][n] = lb;
    }

    int w = t >> 6, ln = t & 63, l15 = ln & 15, lh = ln >> 4;
    int wr = (w >> 1) * 64, wc = (w & 1) * 64;
    bool lh0 = (lh == 0);
    f32x4 z4 = {0.f, 0.f, 0.f, 0.f};
    bf16x8 z8 = {0, 0, 0, 0, 0, 0, 0, 0};
    f32x4 acc[4][4];
#pragma unroll
    for (int i = 0; i < 4; i++)
#pragma unroll
        for (int j = 0; j < 4; j++) acc[i][j] = z4;

    int brr = t >> 3, bkk = (t & 7) * 8;

    for (int k0 = 0; k0 < FF; k0 += 64) {
        __syncthreads();
#pragma unroll
        for (int r = 0; r < 4; r++) {
            int row = brr + r * 32;
            *reinterpret_cast<uint4*>(&Bbh[row][bkk]) =
                *reinterpret_cast<const uint4*>(&W2th[(size_t)(n0 + row) * FF + k0 + bkk]);
            *reinterpret_cast<uint4*>(&Bbl[row][bkk]) =
                *reinterpret_cast<const uint4*>(&W2tl[(size_t)(n0 + row) * FF + k0 + bkk]);
        }
        bf16x8 wh[4], wl[4];
#pragma unroll
        for (int fq = 0; fq < 4; fq++) {
            bf16x8 h8 = *reinterpret_cast<const bf16x8*>(&W1th[(size_t)(k0 + fq * 16 + l15) * 8]);
            bf16x8 l8 = *reinterpret_cast<const bf16x8*>(&W1tl[(size_t)(k0 + fq * 16 + l15) * 8]);
            wh[fq] = lh0 ? h8 : z8;
            wl[fq] = lh0 ? l8 : z8;
        }
#pragma unroll
        for (int mqi = 0; mqi < 2; mqi++) {
            int m = (w * 2 + mqi) * 16 + l15;
            int mrow = lh0 ? m : 128;
            bf16x8 qh  = *reinterpret_cast<const bf16x8*>(&qsh[mrow][0]);
            bf16x8 ql_ = *reinterpret_cast<const bf16x8*>(&qsl[mrow][0]);
#pragma unroll
            for (int fq = 0; fq < 4; fq++) {
                f32x4 d = z4;
                d = MFMA(wh[fq], qh, d);
                d = MFMA(wh[fq], ql_, d);
                d = MFMA(wl[fq], qh, d);
                float4 b1v = *reinterpret_cast<const float4*>(&b1[k0 + fq * 16 + lh * 4]);
                float v0 = fmaxf(d[0] + b1v.x, 0.f);
                float v1 = fmaxf(d[1] + b1v.y, 0.f);
                float v2 = fmaxf(d[2] + b1v.z, 0.f);
                float v3 = fmaxf(d[3] + b1v.w, 0.f);
                ushort_t h0_, l0_, h1_, l1_, h2_, l2_, h3_, l3_;
                tsplit_fast(v0, h0_, l0_);
                tsplit_fast(v1, h1_, l1_);
                tsplit_fast(v2, h2_, l2_);
                tsplit_fast(v3, h3_, l3_);
                uint2 hu, lu;
                hu.x = (uint)h0_ | ((uint)h1_ << 16);
                hu.y = (uint)h2_ | ((uint)h3_ << 16);
                lu.x = (uint)l0_ | ((uint)l1_ << 16);
                lu.y = (uint)l2_ | ((uint)l3_ << 16);
                *reinterpret_cast<uint2*>(&Abh[m][fq * 16 + lh * 4]) = hu;
                *reinterpret_cast<uint2*>(&Abl[m][fq * 16 + lh * 4]) = lu;
            }
        }
        __syncthreads();
#pragma unroll
        for (int ks = 0; ks < 2; ks++) {
            bf16x8 ah[4], al_[4];
#pragma unroll
            for (int mt = 0; mt < 4; mt++) {
                ah[mt]  = *reinterpret_cast<const bf16x8*>(&Abh[wr + mt * 16 + l15][ks * 32 + lh * 8]);
                al_[mt] = *reinterpret_cast<const bf16x8*>(&Abl[wr + mt * 16 + l15][ks * 32 + lh * 8]);
            }
#pragma unroll
            for (int nt = 0; nt < 4; nt++) {
                bf16x8 bh = *reinterpret_cast<const bf16x8*>(&Bbh[wc + nt * 16 + l15][ks * 32 + lh * 8]);
                bf16x8 bl = *reinterpret_cast<const bf16x8*>(&Bbl[wc + nt * 16 + l15][ks * 32 + lh * 8]);
#pragma unroll
                for (int mt = 0; mt < 4; mt++) {
                    acc[mt][nt] = MFMA(ah[mt], bh, acc[mt][nt]);
                    acc[mt][nt] = MFMA(ah[mt], bl, acc[mt][nt]);
                    acc[mt][nt] = MFMA(al_[mt], bh, acc[mt][nt]);
                }
            }
        }
    }
#pragma unroll
    for (int nt = 0; nt < 4; nt++) {
        int col = n0 + wc + nt * 16 + l15;
        float bs = b2[col];
#pragma unroll
        for (int mt = 0; mt < 4; mt++)
#pragma unroll
            for (int r = 0; r < 4; r++)
                outp[(size_t)(m0 + wr + mt * 16 + lh * 4 + r) * DD + col] = acc[mt][nt][r] + bs;
    }
}

// ---------------------------------------------------------------------------
// Kernel 6: pooled[b,d] = mean_s h[b,s,d]
// ---------------------------------------------------------------------------
__global__ __launch_bounds__(256) void pool_mean(const uint* __restrict__ Hp,
                                                 float* __restrict__ pooled) {
    int idx = blockIdx.x * 256 + threadIdx.x;
    if (idx >= BB * DD) return;
    int b = idx >> 9, d = idx & 511;
    float s = 0.f;
    for (int j = 0; j < SS; j++) s += unpackf(Hp[((size_t)b * SS + j) * DD + d]);
    pooled[idx] = s * (1.f / SS);
}

// ---------------------------------------------------------------------------
// Kernel 7: out[b,c] = pooled[b,:] . clf_w[:,c] + clf_b[c]
// ---------------------------------------------------------------------------
__global__ __launch_bounds__(64) void classifier(const float* __restrict__ pooled,
                                                 const float* __restrict__ W,
                                                 const float* __restrict__ bias,
                                                 float* __restrict__ out) {
    int o = blockIdx.x;
    int b = o / CC, c = o % CC;
    int lane = threadIdx.x;
    float s = 0.f;
    for (int d = lane; d < DD; d += 64) s += pooled[b * DD + d] * W[d * CC + c];
#pragma unroll
    for (int off = 32; off > 0; off >>= 1) s += __shfl_xor(s, off);
    if (lane == 0) out[o] = s + bias[c];
}

// ---------------------------------------------------------------------------
extern "C" void kernel_launch(void* const* d_in, const int* in_sizes, int n_in,
                              void* d_out, int out_size, void* d_ws, size_t ws_size,
                              hipStream_t stream) {
    (void)in_sizes; (void)n_in; (void)out_size; (void)ws_size;
    const int*   x      = (const int*)d_in[0];
    const float* emb    = (const float*)d_in[1];
    const float* ln1_g  = (const float*)d_in[2];
    const float* ln1_b  = (const float*)d_in[3];
    const float* ln2_g  = (const float*)d_in[4];
    const float* ln2_b  = (const float*)d_in[5];
    const float* attn_w = (const float*)d_in[6];
    const float* attn_b = (const float*)d_in[7];
    const float* theta  = (const float*)d_in[8];
    const float* ffn_w1 = (const float*)d_in[9];
    const float* ffn_b1 = (const float*)d_in[10];
    const float* ffn_w2 = (const float*)d_in[11];
    const float* ffn_b2 = (const float*)d_in[12];
    const float* clf_w  = (const float*)d_in[13];
    const float* clf_b  = (const float*)d_in[14];
    float* out = (float*)d_out;

    char* ws = (char*)d_ws;
    uint*     Hp     = (uint*)(ws);                     // 32 MB packed hi|lo
    float*    t2     = (float*)(ws + 33554432);         // 32 MB fp32
    ushort_t* t1h    = (ushort_t*)(ws + 67108864);      // 16 MB bf16 hi
    ushort_t* t1l    = (ushort_t*)(ws + 83886080);      // 16 MB bf16 lo
    float*    pooled = (float*)(ws + 100663296);        // 64 KB
    ushort_t* Wath   = (ushort_t*)(ws + 100728832);     // 512 KB attn_w hi
    ushort_t* Watl   = (ushort_t*)(ws + 101253120);     // 512 KB attn_w lo
    ushort_t* W1th6  = (ushort_t*)(ws + 101777408);     // 192 KB W1t hi
    ushort_t* W1tl6  = (ushort_t*)(ws + 101974016);     // 192 KB W1t lo
    ushort_t* W2th   = (ushort_t*)(ws + 67108864);      // reuses t1h region
    ushort_t* W2tl   = (ushort_t*)(ws + 67108864 + 2097152);

    embed_pe<<<(BB * SS * DD + 255) / 256, 256, 0, stream>>>(x, emb, Hp);
    prep_w1t<<<dim3(FF / 256, LL), 256, 0, stream>>>(ffn_w1, W1th6, W1tl6);

    for (int l = 0; l < LL; l++) {
        flash_attn_split<<<dim3(SS / 128, HH, BB), 512, 0, stream>>>(Hp, t1h, t1l);
        transpose_split_w<<<(DD / 64) * (DD / 64), 256, 0, stream>>>(
            attn_w + (size_t)l * DD * DD, Wath, Watl, DD, DD);
        gemm_split<<<(16384 / 128) * (DD / 128), 256, 0, stream>>>(
            t1h, t1l, Wath, Watl, attn_b + l * DD, t2, BB * SS, DD, DD);
        ln_residual<<<BB * SS / 4, 256, 0, stream>>>(Hp, t2, ln1_g + l * DD, ln1_b + l * DD);
        transpose_split_w<<<(FF / 64) * (DD / 64), 256, 0, stream>>>(
            ffn_w2 + (size_t)l * FF * DD, W2th, W2tl, FF, DD);
        ffn_split<<<(16384 / 128) * (DD / 128), 256, 0, stream>>>(
            Hp, W1th6 + (size_t)l * FF * 8, W1tl6 + (size_t)l * FF * 8, ffn_b1 + l * FF,
            W2th, W2tl, ffn_b2 + l * DD, theta + l * NQ, t2);
        ln_residual<<<BB * SS / 4, 256, 0, stream>>>(Hp, t2, ln2_g + l * DD, ln2_b + l * DD);
    }

    pool_mean<<<(BB * DD + 255) / 256, 256, 0, stream>>>(Hp, pooled);
    classifier<<<BB * CC, 64, 0, stream>>>(pooled, clf_w, clf_b, out);
}